// Round 17
// baseline (157.776 us; speedup 1.0000x reference)
//
#include <hip/hip_runtime.h>

#define NN 100000
#define NE 1600000
#define DD 128
#define BSH 8           // dst bucket = 256 nodes
#define NB 391          // ceil(NN/256)
#define CAP 4608        // per-dst-bucket partition capacity (mean 4092, +8 sigma)
#define CAPP 8704       // per-dst-bucket csr capacity incl. per-node pad-to-16 (mean ~6140)
#define SSH 9           // src bucket = 512 nodes
#define NBS 196         // ceil(NN/512)
#define CAP2 9472       // per-src-bucket capacity (mean 8163, +14 sigma)
#define NGB 782         // gemm blocks: ceil(NN/128)
#define NAB 6250        // agg1 blocks: 6250 * 4 waves * 4 nodes = 100000
#define NRB 125         // red1 blocks (each sums 50 partial rows)

typedef float f32x2 __attribute__((ext_vector_type(2)));
typedef float f32x4 __attribute__((ext_vector_type(4)));
typedef short s16x8 __attribute__((ext_vector_type(8)));

static __device__ __forceinline__ unsigned short f2bf(float f) {
    unsigned u = __float_as_uint(f);
    return (unsigned short)((u + 0x7fffu + ((u >> 16) & 1u)) >> 16);
}

// ---------------- dual partition: dst-stream (391 buckets) + src-stream (196 buckets) ----------------
// dst record = (local_dst 8b << 17) | src 17b ; src record = (local_src 9b << 17) | dst 17b

__global__ __launch_bounds__(256) void k_part(const int* __restrict__ src, const int* __restrict__ dst,
                                              int* __restrict__ bcursor, int* __restrict__ bcursor2,
                                              unsigned* __restrict__ part, unsigned* __restrict__ part2) {
    __shared__ int histD[NB], rankD[NB], bblD[NB];
    __shared__ int histS[NBS], rankS[NBS], bblS[NBS];
    int t = threadIdx.x;
    for (int j = t; j < NB; j += 256) histD[j] = 0;
    if (t < NBS) histS[t] = 0;
    __syncthreads();
    int base = blockIdx.x * 4096;
    int s[16], d[16];
    #pragma unroll
    for (int j = 0; j < 16; j++) {
        int i = base + j * 256 + t;
        if (i < NE) {
            s[j] = src[i]; d[j] = dst[i];
            atomicAdd(&histD[d[j] >> BSH], 1);
            atomicAdd(&histS[s[j] >> SSH], 1);
        } else d[j] = -1;
    }
    __syncthreads();
    for (int j = t; j < NB; j += 256) { bblD[j] = atomicAdd(&bcursor[j], histD[j]);  rankD[j] = 0; }
    if (t < NBS) { bblS[t] = atomicAdd(&bcursor2[t], histS[t]); rankS[t] = 0; }
    __syncthreads();
    #pragma unroll
    for (int j = 0; j < 16; j++) {
        if (d[j] >= 0) {
            int bD = d[j] >> BSH;
            int r = bblD[bD] + atomicAdd(&rankD[bD], 1);
            if (r < CAP)
                part[(size_t)bD * CAP + r] = (unsigned)s[j] | ((unsigned)(d[j] & 255) << 17);
            int bS = s[j] >> SSH;
            int r2 = bblS[bS] + atomicAdd(&rankS[bS], 1);
            if (r2 < CAP2)
                part2[(size_t)bS * CAP2 + r2] = (unsigned)d[j] | ((unsigned)(s[j] & 511) << 17);
        }
    }
}

// ---------------- per-bucket (256 nodes) CSR + scatter, per-node segments padded to 16 ----------------
// Pad entries hold NN (zero dummy hs row) so agg1's inner loop needs no bounds checks.

__global__ __launch_bounds__(256) void k_csr(const unsigned* __restrict__ part, const int* __restrict__ bcursor,
                                             int* __restrict__ offs, int* __restrict__ oend,
                                             float* __restrict__ dis, int* __restrict__ csr,
                                             unsigned* __restrict__ hs) {
    __shared__ int cnt[256], offl[256], s2[256];
    int t = threadIdx.x;
    int b = blockIdx.x;
    if (b == 0 && t < 32) hs[(unsigned)NN * 32u + t] = 0u;   // zero dummy row (before k_agg1)
    int dlo = b << BSH;
    int nn_b = NN - dlo; if (nn_b > 256) nn_b = 256;
    int c = bcursor[b]; if (c > CAP) c = CAP;
    size_t e0 = (size_t)b * CAP;
    int e0p = b * CAPP;
    cnt[t] = 0;
    __syncthreads();
    for (int i = t; i < c; i += 256)
        atomicAdd(&cnt[part[e0 + i] >> 17], 1);
    __syncthreads();
    int a = cnt[t];
    int ap = (a + 15) & ~15;
    s2[t] = ap;
    __syncthreads();
    for (int off = 1; off < 256; off <<= 1) {
        int add = (t >= off) ? s2[t - off] : 0;
        __syncthreads();
        s2[t] += add;
        __syncthreads();
    }
    int ex = s2[t] - ap;
    offl[t] = ex;
    if (t < nn_b) {
        offs[dlo + t] = e0p + ex;
        oend[dlo + t] = e0p + ex + ap;       // padded end = loop bound
        dis[dlo + t] = rsqrtf((float)a + 1.0f);
    }
    cnt[t] = 0;
    __syncthreads();
    for (int i = t; i < c; i += 256) {
        unsigned e = part[e0 + i];
        int li = (int)(e >> 17);
        int p = e0p + offl[li] + atomicAdd(&cnt[li], 1);
        csr[p] = (int)(e & 0x1FFFFu);
    }
    __syncthreads();
    if (t < nn_b) {
        int base2 = e0p + offl[t];
        for (int i = a; i < ap; i++) csr[base2 + i] = NN;   // pad with dummy index
    }
}

// ---------------- merged: blocks [0,NGB) = MFMA GEMM; [NGB,NGB+NBS) = coef ----------------
// Both branches only READ k_csr outputs (dis); they write disjoint buffers (hs vs coef).

__global__ __launch_bounds__(256) void k_gemmcoef(const float* __restrict__ Ap, const float* __restrict__ W,
                                                  const float* __restrict__ dis, unsigned* __restrict__ hs,
                                                  const unsigned* __restrict__ part2, const int* __restrict__ bcursor2,
                                                  float* __restrict__ coef) {
    __shared__ unsigned WF[8192];   // gemm: 32KB bf16 W fragments; coef branch reuses as float accL
    int tid = threadIdx.x;
    if (blockIdx.x >= NGB) {
        // ---- coef branch (src-buckets, LDS f32 accumulation) ----
        float* accL = (float*)WF;
        int b = blockIdx.x - NGB;
        int dlo = b << SSH;
        int nn_b = NN - dlo; if (nn_b > 512) nn_b = 512;
        int c = bcursor2[b]; if (c > CAP2) c = CAP2;
        size_t e0 = (size_t)b * CAP2;
        accL[tid] = 0.f; accL[tid + 256] = 0.f;
        __syncthreads();
        for (int i = tid; i < c; i += 256) {
            unsigned e = part2[e0 + i];
            atomicAdd(&accL[e >> 17], dis[e & 0x1FFFFu]);
        }
        __syncthreads();
        #pragma unroll
        for (int q = 0; q < 2; q++) {
            int i = tid + q * 256;
            if (i < nn_b) coef[dlo + i] = accL[i];
        }
        return;
    }

    // ---- gemm branch ----
    #pragma unroll
    for (int i = 0; i < 32; i++) {
        int e = i * 256 + tid;
        int jw = e & 3, lane = (e >> 2) & 63, kk = (e >> 8) & 3, nt = e >> 10;
        int r0 = kk * 32 + ((lane >> 4) << 3) + (jw << 1);
        int c = (nt << 4) + (lane & 15);
        unsigned lo = f2bf(W[r0 * DD + c]);
        unsigned hi = f2bf(W[(r0 + 1) * DD + c]);
        WF[e] = lo | (hi << 16);
    }

    int lane = tid & 63;
    int w = tid >> 6;
    int rowBase = blockIdx.x * 128 + w * 32;
    int lg = lane >> 4;
    int ll = lane & 15;

    // load + convert x to bf16 fragments before the barrier (overlaps W staging wait)
    s16x8 af[2][4];
    #pragma unroll
    for (int mt = 0; mt < 2; mt++) {
        int r = rowBase + mt * 16 + ll;
        if (r >= NN) r = NN - 1;
        const char* xp = (const char*)Ap + ((unsigned)r * 512u + (unsigned)lg * 32u);
        #pragma unroll
        for (int kk = 0; kk < 4; kk++) {
            f32x4 a0 = *(const f32x4*)(xp + kk * 128);
            f32x4 a1 = *(const f32x4*)(xp + kk * 128 + 16);
            s16x8 tt;
            tt[0] = (short)f2bf(a0[0]); tt[1] = (short)f2bf(a0[1]);
            tt[2] = (short)f2bf(a0[2]); tt[3] = (short)f2bf(a0[3]);
            tt[4] = (short)f2bf(a1[0]); tt[5] = (short)f2bf(a1[1]);
            tt[6] = (short)f2bf(a1[2]); tt[7] = (short)f2bf(a1[3]);
            af[mt][kk] = tt;
        }
    }
    __syncthreads();

    f32x4 acc[2][8];
    #pragma unroll
    for (int m = 0; m < 2; m++)
        #pragma unroll
        for (int n = 0; n < 8; n++) acc[m][n] = (f32x4){0.f, 0.f, 0.f, 0.f};

    const s16x8* wfrag = (const s16x8*)WF;

    #pragma unroll
    for (int kk = 0; kk < 4; kk++) {
        #pragma unroll
        for (int nt = 0; nt < 8; nt++) {
            s16x8 bf = wfrag[(nt * 4 + kk) * 64 + lane];
            acc[0][nt] = __builtin_amdgcn_mfma_f32_16x16x32_bf16(bf, af[0][kk], acc[0][nt], 0, 0, 0);
            acc[1][nt] = __builtin_amdgcn_mfma_f32_16x16x32_bf16(bf, af[1][kk], acc[1][nt], 0, 0, 0);
        }
    }

    #pragma unroll
    for (int mt = 0; mt < 2; mt++) {
        int grow = rowBase + mt * 16 + ll;
        if (grow < NN) {
            float dn = dis[grow];
            unsigned* orow = (unsigned*)((char*)hs + ((unsigned)grow * 128u));
            #pragma unroll
            for (int nt = 0; nt < 8; nt++) {
                f32x4 v = acc[mt][nt];
                int u = 0;
                u = __builtin_amdgcn_cvt_pk_fp8_f32(v[0] * dn, v[1] * dn, u, false);
                u = __builtin_amdgcn_cvt_pk_fp8_f32(v[2] * dn, v[3] * dn, u, true);
                orow[nt * 4 + lg] = (unsigned)u;
            }
        }
    }
}

// ---------------- Fused agg1 + wsum: branch-free loop with int4 index prefetch ----------------

__global__ __launch_bounds__(256) void k_agg1(const unsigned* __restrict__ hs4, const float* __restrict__ dis,
                                              const int* __restrict__ offs, const int* __restrict__ oend,
                                              const int* __restrict__ csr, const float* __restrict__ bias,
                                              const float* __restrict__ coef, float* __restrict__ partials) {
    __shared__ float red[4][DD];
    int lane = threadIdx.x & 63;
    int half = lane >> 5;
    int li = lane & 31;
    int wv = threadIdx.x >> 6;
    int node0 = (blockIdx.x * 4 + wv) * 4;
    unsigned li4 = (unsigned)li << 2;
    const char* hb = (const char*)hs4;
    f32x2 v01 = {0.f, 0.f}, v23 = {0.f, 0.f};
    f32x4 bv = *(const f32x4*)&bias[li * 4];

    #pragma unroll 1
    for (int q = 0; q < 4; q++) {
        int node = node0 + q;
        int beg = offs[node], endp = oend[node];
        float dn = dis[node];
        f32x2 a01 = {0.f, 0.f}, a23 = {0.f, 0.f};

        const int* cp0 = csr + beg + half * 8;
        int4 ca = *(const int4*)cp0;
        int4 cb = *(const int4*)(cp0 + 4);
        #pragma unroll 1
        for (int i = beg; i < endp; i += 16) {
            const int* np = csr + i + 16 + half * 8;   // guard-allocated tail: safe over-read
            int4 na = *(const int4*)np;
            int4 nb = *(const int4*)(np + 4);
            unsigned r[8];
            r[0] = *(const unsigned*)(hb + (((unsigned)ca.x << 7) + li4));
            r[1] = *(const unsigned*)(hb + (((unsigned)ca.y << 7) + li4));
            r[2] = *(const unsigned*)(hb + (((unsigned)ca.z << 7) + li4));
            r[3] = *(const unsigned*)(hb + (((unsigned)ca.w << 7) + li4));
            r[4] = *(const unsigned*)(hb + (((unsigned)cb.x << 7) + li4));
            r[5] = *(const unsigned*)(hb + (((unsigned)cb.y << 7) + li4));
            r[6] = *(const unsigned*)(hb + (((unsigned)cb.z << 7) + li4));
            r[7] = *(const unsigned*)(hb + (((unsigned)cb.w << 7) + li4));
            #pragma unroll
            for (int j = 0; j < 8; j++) {
                a01 += __builtin_amdgcn_cvt_pk_f32_fp8(r[j], false);
                a23 += __builtin_amdgcn_cvt_pk_f32_fp8(r[j], true);
            }
            ca = na; cb = nb;
        }

        a01[0] += __shfl_xor(a01[0], 32);
        a01[1] += __shfl_xor(a01[1], 32);
        a23[0] += __shfl_xor(a23[0], 32);
        a23[1] += __shfl_xor(a23[1], 32);

        if (half == 0) {
            unsigned su = *(const unsigned*)(hb + (((unsigned)node << 7) + li4));
            f32x2 sl = __builtin_amdgcn_cvt_pk_f32_fp8(su, false);
            f32x2 sh = __builtin_amdgcn_cvt_pk_f32_fp8(su, true);
            float o0 = fmaxf(dn * (a01[0] + sl[0]) + bv[0], 0.f);
            float o1 = fmaxf(dn * (a01[1] + sl[1]) + bv[1], 0.f);
            float o2 = fmaxf(dn * (a23[0] + sh[0]) + bv[2], 0.f);
            float o3 = fmaxf(dn * (a23[1] + sh[1]) + bv[3], 0.f);
            float wt = (coef[node] + dn) * dn;
            v01[0] += wt * o0; v01[1] += wt * o1;
            v23[0] += wt * o2; v23[1] += wt * o3;
        }
    }

    if (half == 0) {
        red[wv][li * 4 + 0] = v01[0];
        red[wv][li * 4 + 1] = v01[1];
        red[wv][li * 4 + 2] = v23[0];
        red[wv][li * 4 + 3] = v23[1];
    }
    __syncthreads();
    int t = threadIdx.x;
    if (t < DD)
        partials[(size_t)blockIdx.x * DD + t] = red[0][t] + red[1][t] + red[2][t] + red[3][t];
}

// ---------------- reductions + final matvec ----------------

__global__ __launch_bounds__(128) void k_red1(const float* __restrict__ partials, float* __restrict__ s1) {
    int t = threadIdx.x, b = blockIdx.x;
    float s = 0.f;
    for (int r = b * 50; r < b * 50 + 50; r++) s += partials[(size_t)r * DD + t];
    s1[b * DD + t] = s;
}

__global__ __launch_bounds__(128) void k_out(const float* __restrict__ s1, const float* __restrict__ W2,
                                             const float* __restrict__ b2, float* __restrict__ out) {
    __shared__ float v[DD];
    int t = threadIdx.x;
    float s = 0.f;
    for (int r = 0; r < NRB; r++) s += s1[r * DD + t];
    v[t] = s * (1.0f / NN);
    __syncthreads();
    float o = b2[t];
    for (int k = 0; k < DD; k++) o += v[k] * W2[k * DD + t];
    out[t] = o;
}

// ---------------- launch ----------------

extern "C" void kernel_launch(void* const* d_in, const int* in_sizes, int n_in,
                              void* d_out, int out_size, void* d_ws, size_t ws_size,
                              hipStream_t stream) {
    const float* x  = (const float*)d_in[0];
    const int*   ei = (const int*)d_in[1];
    const float* W1 = (const float*)d_in[2];
    const float* b1 = (const float*)d_in[3];
    const float* W2 = (const float*)d_in[4];
    const float* b2 = (const float*)d_in[5];
    float* out = (float*)d_out;
    const int* esrc = ei;
    const int* edst = ei + NE;

    char* p = (char*)d_ws;
    unsigned* part  = (unsigned*)p;      p += (size_t)NB * CAP * 4;
    unsigned* part2 = (unsigned*)p;      p += (size_t)NBS * CAP2 * 4;
    int* csr       = (int*)p;            p += (size_t)(NB * CAPP + 16) * 4;   // +16 prefetch guard
    int* offs      = (int*)p;            p += (((size_t)NN * 4) + 255) & ~(size_t)255;
    int* oend      = (int*)p;            p += (((size_t)NN * 4) + 255) & ~(size_t)255;
    float* dis     = (float*)p;          p += (((size_t)NN * 4) + 255) & ~(size_t)255;
    float* coef    = (float*)p;          p += (((size_t)NN * 4) + 255) & ~(size_t)255;
    int* bcursor   = (int*)p;            p += (((size_t)(NB + NBS) * 4) + 255) & ~(size_t)255;
    unsigned* hs   = (unsigned*)p;       p += (size_t)(NN + 1) * DD;    // fp8 rows + zero dummy row
    float* partials = (float*)p;         p += (size_t)NAB * DD * 4;
    float* s1      = (float*)p;          p += (size_t)NRB * DD * 4;
    int* bcursor2  = bcursor + NB;

    hipMemsetAsync(bcursor, 0, (NB + NBS) * 4, stream);

    k_part<<<(NE + 4095) / 4096, 256, 0, stream>>>(esrc, edst, bcursor, bcursor2, part, part2);
    k_csr<<<NB, 256, 0, stream>>>(part, bcursor, offs, oend, dis, csr, hs);

    k_gemmcoef<<<NGB + NBS, 256, 0, stream>>>(x, W1, dis, hs, part2, bcursor2, coef);
    k_agg1<<<NAB, 256, 0, stream>>>(hs, dis, offs, oend, csr, b1, coef, partials);

    k_red1<<<NRB, 128, 0, stream>>>(partials, s1);
    k_out<<<1, 128, 0, stream>>>(s1, W2, b2, out);
}

// Round 18
// 157.715 us; speedup vs baseline: 1.0004x; 1.0004x over previous
//
#include <hip/hip_runtime.h>

#define NN 100000
#define NE 1600000
#define DD 128
#define BSH 8           // dst bucket = 256 nodes
#define NB 391          // ceil(NN/256)
#define CAP 4608        // per-dst-bucket partition capacity (mean 4092, +8 sigma)
#define CAPP 8704       // per-dst-bucket csr capacity incl. per-node pad-to-16 (mean ~6140)
#define SSH 9           // src bucket = 512 nodes
#define NBS 196         // ceil(NN/512)
#define CAP2 9472       // per-src-bucket capacity (mean 8163, +14 sigma)
#define NGB 782         // gemm blocks: ceil(NN/128)
#define NAB 6250        // agg1 blocks: 6250 * 4 waves * 4 nodes = 100000
#define NRB 125         // red1 blocks (each sums 50 partial rows)

typedef float f32x2 __attribute__((ext_vector_type(2)));
typedef float f32x4 __attribute__((ext_vector_type(4)));
typedef short s16x8 __attribute__((ext_vector_type(8)));

static __device__ __forceinline__ unsigned short f2bf(float f) {
    unsigned u = __float_as_uint(f);
    return (unsigned short)((u + 0x7fffu + ((u >> 16) & 1u)) >> 16);
}

// ---------------- dual partition: dst-stream (391 buckets) + src-stream (196 buckets) ----------------
// dst record = (local_dst 8b << 17) | src 17b ; src record = (local_src 9b << 17) | dst 17b

__global__ __launch_bounds__(256) void k_part(const int* __restrict__ src, const int* __restrict__ dst,
                                              int* __restrict__ bcursor, int* __restrict__ bcursor2,
                                              unsigned* __restrict__ part, unsigned* __restrict__ part2) {
    __shared__ int histD[NB], rankD[NB], bblD[NB];
    __shared__ int histS[NBS], rankS[NBS], bblS[NBS];
    int t = threadIdx.x;
    for (int j = t; j < NB; j += 256) histD[j] = 0;
    if (t < NBS) histS[t] = 0;
    __syncthreads();
    int base = blockIdx.x * 4096;
    int s[16], d[16];
    #pragma unroll
    for (int j = 0; j < 16; j++) {
        int i = base + j * 256 + t;
        if (i < NE) {
            s[j] = src[i]; d[j] = dst[i];
            atomicAdd(&histD[d[j] >> BSH], 1);
            atomicAdd(&histS[s[j] >> SSH], 1);
        } else d[j] = -1;
    }
    __syncthreads();
    for (int j = t; j < NB; j += 256) { bblD[j] = atomicAdd(&bcursor[j], histD[j]);  rankD[j] = 0; }
    if (t < NBS) { bblS[t] = atomicAdd(&bcursor2[t], histS[t]); rankS[t] = 0; }
    __syncthreads();
    #pragma unroll
    for (int j = 0; j < 16; j++) {
        if (d[j] >= 0) {
            int bD = d[j] >> BSH;
            int r = bblD[bD] + atomicAdd(&rankD[bD], 1);
            if (r < CAP)
                part[(size_t)bD * CAP + r] = (unsigned)s[j] | ((unsigned)(d[j] & 255) << 17);
            int bS = s[j] >> SSH;
            int r2 = bblS[bS] + atomicAdd(&rankS[bS], 1);
            if (r2 < CAP2)
                part2[(size_t)bS * CAP2 + r2] = (unsigned)d[j] | ((unsigned)(s[j] & 511) << 17);
        }
    }
}

// ---------------- per-bucket (256 nodes) CSR + scatter, per-node segments padded to 16 ----------------
// Pad entries hold NN (zero dummy hs row) so agg1's inner loop needs no bounds checks.

__global__ __launch_bounds__(256) void k_csr(const unsigned* __restrict__ part, const int* __restrict__ bcursor,
                                             int* __restrict__ offs, int* __restrict__ oend,
                                             float* __restrict__ dis, int* __restrict__ csr,
                                             unsigned* __restrict__ hs) {
    __shared__ int cnt[256], offl[256], s2[256];
    int t = threadIdx.x;
    int b = blockIdx.x;
    if (b == 0 && t < 32) hs[(unsigned)NN * 32u + t] = 0u;   // zero dummy row (before k_agg1)
    int dlo = b << BSH;
    int nn_b = NN - dlo; if (nn_b > 256) nn_b = 256;
    int c = bcursor[b]; if (c > CAP) c = CAP;
    size_t e0 = (size_t)b * CAP;
    int e0p = b * CAPP;
    cnt[t] = 0;
    __syncthreads();
    for (int i = t; i < c; i += 256)
        atomicAdd(&cnt[part[e0 + i] >> 17], 1);
    __syncthreads();
    int a = cnt[t];
    int ap = (a + 15) & ~15;
    s2[t] = ap;
    __syncthreads();
    for (int off = 1; off < 256; off <<= 1) {
        int add = (t >= off) ? s2[t - off] : 0;
        __syncthreads();
        s2[t] += add;
        __syncthreads();
    }
    int ex = s2[t] - ap;
    offl[t] = ex;
    if (t < nn_b) {
        offs[dlo + t] = e0p + ex;
        oend[dlo + t] = e0p + ex + ap;       // padded end = loop bound
        dis[dlo + t] = rsqrtf((float)a + 1.0f);
    }
    cnt[t] = 0;
    __syncthreads();
    for (int i = t; i < c; i += 256) {
        unsigned e = part[e0 + i];
        int li = (int)(e >> 17);
        int p = e0p + offl[li] + atomicAdd(&cnt[li], 1);
        csr[p] = (int)(e & 0x1FFFFu);
    }
    __syncthreads();
    if (t < nn_b) {
        int base2 = e0p + offl[t];
        for (int i = a; i < ap; i++) csr[base2 + i] = NN;   // pad with dummy index
    }
}

// ---------------- merged: blocks [0,NGB) = MFMA GEMM; [NGB,NGB+NBS) = coef ----------------
// Both branches only READ k_csr outputs (dis); they write disjoint buffers (hs vs coef).

__global__ __launch_bounds__(256) void k_gemmcoef(const float* __restrict__ Ap, const float* __restrict__ W,
                                                  const float* __restrict__ dis, unsigned* __restrict__ hs,
                                                  const unsigned* __restrict__ part2, const int* __restrict__ bcursor2,
                                                  float* __restrict__ coef) {
    __shared__ unsigned WF[8192];   // gemm: 32KB bf16 W fragments; coef branch reuses as float accL
    int tid = threadIdx.x;
    if (blockIdx.x >= NGB) {
        // ---- coef branch (src-buckets, LDS f32 accumulation) ----
        float* accL = (float*)WF;
        int b = blockIdx.x - NGB;
        int dlo = b << SSH;
        int nn_b = NN - dlo; if (nn_b > 512) nn_b = 512;
        int c = bcursor2[b]; if (c > CAP2) c = CAP2;
        size_t e0 = (size_t)b * CAP2;
        accL[tid] = 0.f; accL[tid + 256] = 0.f;
        __syncthreads();
        for (int i = tid; i < c; i += 256) {
            unsigned e = part2[e0 + i];
            atomicAdd(&accL[e >> 17], dis[e & 0x1FFFFu]);
        }
        __syncthreads();
        #pragma unroll
        for (int q = 0; q < 2; q++) {
            int i = tid + q * 256;
            if (i < nn_b) coef[dlo + i] = accL[i];
        }
        return;
    }

    // ---- gemm branch ----
    #pragma unroll
    for (int i = 0; i < 32; i++) {
        int e = i * 256 + tid;
        int jw = e & 3, lane = (e >> 2) & 63, kk = (e >> 8) & 3, nt = e >> 10;
        int r0 = kk * 32 + ((lane >> 4) << 3) + (jw << 1);
        int c = (nt << 4) + (lane & 15);
        unsigned lo = f2bf(W[r0 * DD + c]);
        unsigned hi = f2bf(W[(r0 + 1) * DD + c]);
        WF[e] = lo | (hi << 16);
    }

    int lane = tid & 63;
    int w = tid >> 6;
    int rowBase = blockIdx.x * 128 + w * 32;
    int lg = lane >> 4;
    int ll = lane & 15;

    // load + convert x to bf16 fragments before the barrier (overlaps W staging wait)
    s16x8 af[2][4];
    #pragma unroll
    for (int mt = 0; mt < 2; mt++) {
        int r = rowBase + mt * 16 + ll;
        if (r >= NN) r = NN - 1;
        const char* xp = (const char*)Ap + ((unsigned)r * 512u + (unsigned)lg * 32u);
        #pragma unroll
        for (int kk = 0; kk < 4; kk++) {
            f32x4 a0 = *(const f32x4*)(xp + kk * 128);
            f32x4 a1 = *(const f32x4*)(xp + kk * 128 + 16);
            s16x8 tt;
            tt[0] = (short)f2bf(a0[0]); tt[1] = (short)f2bf(a0[1]);
            tt[2] = (short)f2bf(a0[2]); tt[3] = (short)f2bf(a0[3]);
            tt[4] = (short)f2bf(a1[0]); tt[5] = (short)f2bf(a1[1]);
            tt[6] = (short)f2bf(a1[2]); tt[7] = (short)f2bf(a1[3]);
            af[mt][kk] = tt;
        }
    }
    __syncthreads();

    f32x4 acc[2][8];
    #pragma unroll
    for (int m = 0; m < 2; m++)
        #pragma unroll
        for (int n = 0; n < 8; n++) acc[m][n] = (f32x4){0.f, 0.f, 0.f, 0.f};

    const s16x8* wfrag = (const s16x8*)WF;

    #pragma unroll
    for (int kk = 0; kk < 4; kk++) {
        #pragma unroll
        for (int nt = 0; nt < 8; nt++) {
            s16x8 bf = wfrag[(nt * 4 + kk) * 64 + lane];
            acc[0][nt] = __builtin_amdgcn_mfma_f32_16x16x32_bf16(bf, af[0][kk], acc[0][nt], 0, 0, 0);
            acc[1][nt] = __builtin_amdgcn_mfma_f32_16x16x32_bf16(bf, af[1][kk], acc[1][nt], 0, 0, 0);
        }
    }

    #pragma unroll
    for (int mt = 0; mt < 2; mt++) {
        int grow = rowBase + mt * 16 + ll;
        if (grow < NN) {
            float dn = dis[grow];
            unsigned* orow = (unsigned*)((char*)hs + ((unsigned)grow * 128u));
            #pragma unroll
            for (int nt = 0; nt < 8; nt++) {
                f32x4 v = acc[mt][nt];
                int u = 0;
                u = __builtin_amdgcn_cvt_pk_fp8_f32(v[0] * dn, v[1] * dn, u, false);
                u = __builtin_amdgcn_cvt_pk_fp8_f32(v[2] * dn, v[3] * dn, u, true);
                orow[nt * 4 + lg] = (unsigned)u;
            }
        }
    }
}

// ---------------- Fused agg1 + wsum: branch-free inner loop (round-16 form, no prefetch) ----------------

__global__ __launch_bounds__(256) void k_agg1(const unsigned* __restrict__ hs4, const float* __restrict__ dis,
                                              const int* __restrict__ offs, const int* __restrict__ oend,
                                              const int* __restrict__ csr, const float* __restrict__ bias,
                                              const float* __restrict__ coef, float* __restrict__ partials) {
    __shared__ float red[4][DD];
    int lane = threadIdx.x & 63;
    int half = lane >> 5;
    int li = lane & 31;
    int wv = threadIdx.x >> 6;
    int node0 = (blockIdx.x * 4 + wv) * 4;
    unsigned li4 = (unsigned)li << 2;
    const char* hb = (const char*)hs4;
    f32x2 v01 = {0.f, 0.f}, v23 = {0.f, 0.f};
    f32x4 bv = *(const f32x4*)&bias[li * 4];

    #pragma unroll 1
    for (int q = 0; q < 4; q++) {
        int node = node0 + q;
        int beg = offs[node], endp = oend[node];
        float dn = dis[node];
        f32x2 a01 = {0.f, 0.f}, a23 = {0.f, 0.f};

        #pragma unroll 1
        for (int i = beg; i < endp; i += 16) {
            const int* cp = csr + i + half * 8;
            int4 sa = *(const int4*)cp;
            int4 sb = *(const int4*)(cp + 4);
            unsigned r[8];
            r[0] = *(const unsigned*)(hb + (((unsigned)sa.x << 7) + li4));
            r[1] = *(const unsigned*)(hb + (((unsigned)sa.y << 7) + li4));
            r[2] = *(const unsigned*)(hb + (((unsigned)sa.z << 7) + li4));
            r[3] = *(const unsigned*)(hb + (((unsigned)sa.w << 7) + li4));
            r[4] = *(const unsigned*)(hb + (((unsigned)sb.x << 7) + li4));
            r[5] = *(const unsigned*)(hb + (((unsigned)sb.y << 7) + li4));
            r[6] = *(const unsigned*)(hb + (((unsigned)sb.z << 7) + li4));
            r[7] = *(const unsigned*)(hb + (((unsigned)sb.w << 7) + li4));
            #pragma unroll
            for (int j = 0; j < 8; j++) {
                a01 += __builtin_amdgcn_cvt_pk_f32_fp8(r[j], false);
                a23 += __builtin_amdgcn_cvt_pk_f32_fp8(r[j], true);
            }
        }

        a01[0] += __shfl_xor(a01[0], 32);
        a01[1] += __shfl_xor(a01[1], 32);
        a23[0] += __shfl_xor(a23[0], 32);
        a23[1] += __shfl_xor(a23[1], 32);

        if (half == 0) {
            unsigned su = *(const unsigned*)(hb + (((unsigned)node << 7) + li4));
            f32x2 sl = __builtin_amdgcn_cvt_pk_f32_fp8(su, false);
            f32x2 sh = __builtin_amdgcn_cvt_pk_f32_fp8(su, true);
            float o0 = fmaxf(dn * (a01[0] + sl[0]) + bv[0], 0.f);
            float o1 = fmaxf(dn * (a01[1] + sl[1]) + bv[1], 0.f);
            float o2 = fmaxf(dn * (a23[0] + sh[0]) + bv[2], 0.f);
            float o3 = fmaxf(dn * (a23[1] + sh[1]) + bv[3], 0.f);
            float wt = (coef[node] + dn) * dn;
            v01[0] += wt * o0; v01[1] += wt * o1;
            v23[0] += wt * o2; v23[1] += wt * o3;
        }
    }

    if (half == 0) {
        red[wv][li * 4 + 0] = v01[0];
        red[wv][li * 4 + 1] = v01[1];
        red[wv][li * 4 + 2] = v23[0];
        red[wv][li * 4 + 3] = v23[1];
    }
    __syncthreads();
    int t = threadIdx.x;
    if (t < DD)
        partials[(size_t)blockIdx.x * DD + t] = red[0][t] + red[1][t] + red[2][t] + red[3][t];
}

// ---------------- reductions + final matvec ----------------

__global__ __launch_bounds__(128) void k_red1(const float* __restrict__ partials, float* __restrict__ s1) {
    int t = threadIdx.x, b = blockIdx.x;
    float s = 0.f;
    for (int r = b * 50; r < b * 50 + 50; r++) s += partials[(size_t)r * DD + t];
    s1[b * DD + t] = s;
}

__global__ __launch_bounds__(128) void k_out(const float* __restrict__ s1, const float* __restrict__ W2,
                                             const float* __restrict__ b2, float* __restrict__ out) {
    __shared__ float v[DD];
    int t = threadIdx.x;
    float s = 0.f;
    for (int r = 0; r < NRB; r++) s += s1[r * DD + t];
    v[t] = s * (1.0f / NN);
    __syncthreads();
    float o = b2[t];
    for (int k = 0; k < DD; k++) o += v[k] * W2[k * DD + t];
    out[t] = o;
}

// ---------------- launch ----------------

extern "C" void kernel_launch(void* const* d_in, const int* in_sizes, int n_in,
                              void* d_out, int out_size, void* d_ws, size_t ws_size,
                              hipStream_t stream) {
    const float* x  = (const float*)d_in[0];
    const int*   ei = (const int*)d_in[1];
    const float* W1 = (const float*)d_in[2];
    const float* b1 = (const float*)d_in[3];
    const float* W2 = (const float*)d_in[4];
    const float* b2 = (const float*)d_in[5];
    float* out = (float*)d_out;
    const int* esrc = ei;
    const int* edst = ei + NE;

    char* p = (char*)d_ws;
    unsigned* part  = (unsigned*)p;      p += (size_t)NB * CAP * 4;
    unsigned* part2 = (unsigned*)p;      p += (size_t)NBS * CAP2 * 4;
    int* csr       = (int*)p;            p += (size_t)(NB * CAPP + 16) * 4;
    int* offs      = (int*)p;            p += (((size_t)NN * 4) + 255) & ~(size_t)255;
    int* oend      = (int*)p;            p += (((size_t)NN * 4) + 255) & ~(size_t)255;
    float* dis     = (float*)p;          p += (((size_t)NN * 4) + 255) & ~(size_t)255;
    float* coef    = (float*)p;          p += (((size_t)NN * 4) + 255) & ~(size_t)255;
    int* bcursor   = (int*)p;            p += (((size_t)(NB + NBS) * 4) + 255) & ~(size_t)255;
    unsigned* hs   = (unsigned*)p;       p += (size_t)(NN + 1) * DD;    // fp8 rows + zero dummy row
    float* partials = (float*)p;         p += (size_t)NAB * DD * 4;
    float* s1      = (float*)p;          p += (size_t)NRB * DD * 4;
    int* bcursor2  = bcursor + NB;

    hipMemsetAsync(bcursor, 0, (NB + NBS) * 4, stream);

    k_part<<<(NE + 4095) / 4096, 256, 0, stream>>>(esrc, edst, bcursor, bcursor2, part, part2);
    k_csr<<<NB, 256, 0, stream>>>(part, bcursor, offs, oend, dis, csr, hs);

    k_gemmcoef<<<NGB + NBS, 256, 0, stream>>>(x, W1, dis, hs, part2, bcursor2, coef);
    k_agg1<<<NAB, 256, 0, stream>>>(hs, dis, offs, oend, csr, b1, coef, partials);

    k_red1<<<NRB, 128, 0, stream>>>(partials, s1);
    k_out<<<1, 128, 0, stream>>>(s1, W2, b2, out);
}

// Round 19
// 152.568 us; speedup vs baseline: 1.0341x; 1.0337x over previous
//
#include <hip/hip_runtime.h>

#define NN 100000
#define NE 1600000
#define DD 128
#define BSH 8           // dst bucket = 256 nodes
#define NB 391          // ceil(NN/256)
#define CAP 4608        // per-dst-bucket partition capacity (mean 4092, +8 sigma)
#define CAPP 8704       // per-dst-bucket csr capacity incl. per-node pad-to-16 (mean ~6140)
#define SSH 9           // src bucket = 512 nodes
#define NBS 196         // ceil(NN/512)
#define CAP2 9472       // per-src-bucket capacity (mean 8163, +14 sigma)
#define NGB 782         // gemm blocks: ceil(NN/128)
#define NAB 6250        // agg1 blocks: 6250 * 4 waves * 4 nodes = 100000
#define NRB 125         // red1 blocks (each sums 50 partial rows)

typedef float f32x2 __attribute__((ext_vector_type(2)));
typedef float f32x4 __attribute__((ext_vector_type(4)));
typedef short s16x8 __attribute__((ext_vector_type(8)));

static __device__ __forceinline__ unsigned short f2bf(float f) {
    unsigned u = __float_as_uint(f);
    return (unsigned short)((u + 0x7fffu + ((u >> 16) & 1u)) >> 16);
}

// ---------------- dual partition: dst-stream (391 buckets) + src-stream (196 buckets) ----------------
// dst record = (local_dst 8b << 17) | src 17b ; src record = (local_src 9b << 17) | dst 17b

__global__ __launch_bounds__(256) void k_part(const int* __restrict__ src, const int* __restrict__ dst,
                                              int* __restrict__ bcursor, int* __restrict__ bcursor2,
                                              unsigned* __restrict__ part, unsigned* __restrict__ part2) {
    __shared__ int histD[NB], rankD[NB], bblD[NB];
    __shared__ int histS[NBS], rankS[NBS], bblS[NBS];
    int t = threadIdx.x;
    for (int j = t; j < NB; j += 256) histD[j] = 0;
    if (t < NBS) histS[t] = 0;
    __syncthreads();
    int base = blockIdx.x * 4096;
    int s[16], d[16];
    #pragma unroll
    for (int j = 0; j < 16; j++) {
        int i = base + j * 256 + t;
        if (i < NE) {
            s[j] = src[i]; d[j] = dst[i];
            atomicAdd(&histD[d[j] >> BSH], 1);
            atomicAdd(&histS[s[j] >> SSH], 1);
        } else d[j] = -1;
    }
    __syncthreads();
    for (int j = t; j < NB; j += 256) { bblD[j] = atomicAdd(&bcursor[j], histD[j]);  rankD[j] = 0; }
    if (t < NBS) { bblS[t] = atomicAdd(&bcursor2[t], histS[t]); rankS[t] = 0; }
    __syncthreads();
    #pragma unroll
    for (int j = 0; j < 16; j++) {
        if (d[j] >= 0) {
            int bD = d[j] >> BSH;
            int r = bblD[bD] + atomicAdd(&rankD[bD], 1);
            if (r < CAP)
                part[(size_t)bD * CAP + r] = (unsigned)s[j] | ((unsigned)(d[j] & 255) << 17);
            int bS = s[j] >> SSH;
            int r2 = bblS[bS] + atomicAdd(&rankS[bS], 1);
            if (r2 < CAP2)
                part2[(size_t)bS * CAP2 + r2] = (unsigned)d[j] | ((unsigned)(s[j] & 511) << 17);
        }
    }
}

// ---------------- per-bucket (256 nodes) CSR + scatter, per-node segments padded to 16 ----------------
// Pad entries hold NN (zero dummy hs row) so agg1's inner loop needs no bounds checks.

__global__ __launch_bounds__(256) void k_csr(const unsigned* __restrict__ part, const int* __restrict__ bcursor,
                                             int* __restrict__ offs, int* __restrict__ oend,
                                             float* __restrict__ dis, int* __restrict__ csr,
                                             unsigned* __restrict__ hs) {
    __shared__ int cnt[256], offl[256], s2[256];
    int t = threadIdx.x;
    int b = blockIdx.x;
    if (b == 0 && t < 32) hs[(unsigned)NN * 32u + t] = 0u;   // zero dummy row (before k_agg1)
    int dlo = b << BSH;
    int nn_b = NN - dlo; if (nn_b > 256) nn_b = 256;
    int c = bcursor[b]; if (c > CAP) c = CAP;
    size_t e0 = (size_t)b * CAP;
    int e0p = b * CAPP;
    cnt[t] = 0;
    __syncthreads();
    for (int i = t; i < c; i += 256)
        atomicAdd(&cnt[part[e0 + i] >> 17], 1);
    __syncthreads();
    int a = cnt[t];
    int ap = (a + 15) & ~15;
    s2[t] = ap;
    __syncthreads();
    for (int off = 1; off < 256; off <<= 1) {
        int add = (t >= off) ? s2[t - off] : 0;
        __syncthreads();
        s2[t] += add;
        __syncthreads();
    }
    int ex = s2[t] - ap;
    offl[t] = ex;
    if (t < nn_b) {
        offs[dlo + t] = e0p + ex;
        oend[dlo + t] = e0p + ex + ap;       // padded end = loop bound
        dis[dlo + t] = rsqrtf((float)a + 1.0f);
    }
    cnt[t] = 0;
    __syncthreads();
    for (int i = t; i < c; i += 256) {
        unsigned e = part[e0 + i];
        int li = (int)(e >> 17);
        int p = e0p + offl[li] + atomicAdd(&cnt[li], 1);
        csr[p] = (int)(e & 0x1FFFFu);
    }
    __syncthreads();
    if (t < nn_b) {
        int base2 = e0p + offl[t];
        for (int i = a; i < ap; i++) csr[base2 + i] = NN;   // pad with dummy index
    }
}

// ---------------- merged: blocks [0,NBS) = coef (runs FIRST); [NBS,NBS+NGB) = MFMA GEMM ----------------
// coef blocks dispatched first so their part2 streaming finishes early; the last L2 traffic
// before k_agg1 is gemm's hs writes (keeps hs warm for the gather — the r16 regime).

__global__ __launch_bounds__(256) void k_gemmcoef(const float* __restrict__ Ap, const float* __restrict__ W,
                                                  const float* __restrict__ dis, unsigned* __restrict__ hs,
                                                  const unsigned* __restrict__ part2, const int* __restrict__ bcursor2,
                                                  float* __restrict__ coef) {
    __shared__ unsigned WF[8192];   // gemm: 32KB bf16 W fragments; coef branch reuses as float accL
    int tid = threadIdx.x;
    if (blockIdx.x < NBS) {
        // ---- coef branch (src-buckets, LDS f32 accumulation) ----
        float* accL = (float*)WF;
        int b = blockIdx.x;
        int dlo = b << SSH;
        int nn_b = NN - dlo; if (nn_b > 512) nn_b = 512;
        int c = bcursor2[b]; if (c > CAP2) c = CAP2;
        size_t e0 = (size_t)b * CAP2;
        accL[tid] = 0.f; accL[tid + 256] = 0.f;
        __syncthreads();
        for (int i = tid; i < c; i += 256) {
            unsigned e = part2[e0 + i];
            atomicAdd(&accL[e >> 17], dis[e & 0x1FFFFu]);
        }
        __syncthreads();
        #pragma unroll
        for (int q = 0; q < 2; q++) {
            int i = tid + q * 256;
            if (i < nn_b) coef[dlo + i] = accL[i];
        }
        return;
    }

    // ---- gemm branch ----
    int gb = blockIdx.x - NBS;
    #pragma unroll
    for (int i = 0; i < 32; i++) {
        int e = i * 256 + tid;
        int jw = e & 3, lane = (e >> 2) & 63, kk = (e >> 8) & 3, nt = e >> 10;
        int r0 = kk * 32 + ((lane >> 4) << 3) + (jw << 1);
        int c = (nt << 4) + (lane & 15);
        unsigned lo = f2bf(W[r0 * DD + c]);
        unsigned hi = f2bf(W[(r0 + 1) * DD + c]);
        WF[e] = lo | (hi << 16);
    }

    int lane = tid & 63;
    int w = tid >> 6;
    int rowBase = gb * 128 + w * 32;
    int lg = lane >> 4;
    int ll = lane & 15;

    // load + convert x to bf16 fragments before the barrier (overlaps W staging wait)
    s16x8 af[2][4];
    #pragma unroll
    for (int mt = 0; mt < 2; mt++) {
        int r = rowBase + mt * 16 + ll;
        if (r >= NN) r = NN - 1;
        const char* xp = (const char*)Ap + ((unsigned)r * 512u + (unsigned)lg * 32u);
        #pragma unroll
        for (int kk = 0; kk < 4; kk++) {
            f32x4 a0 = *(const f32x4*)(xp + kk * 128);
            f32x4 a1 = *(const f32x4*)(xp + kk * 128 + 16);
            s16x8 tt;
            tt[0] = (short)f2bf(a0[0]); tt[1] = (short)f2bf(a0[1]);
            tt[2] = (short)f2bf(a0[2]); tt[3] = (short)f2bf(a0[3]);
            tt[4] = (short)f2bf(a1[0]); tt[5] = (short)f2bf(a1[1]);
            tt[6] = (short)f2bf(a1[2]); tt[7] = (short)f2bf(a1[3]);
            af[mt][kk] = tt;
        }
    }
    __syncthreads();

    f32x4 acc[2][8];
    #pragma unroll
    for (int m = 0; m < 2; m++)
        #pragma unroll
        for (int n = 0; n < 8; n++) acc[m][n] = (f32x4){0.f, 0.f, 0.f, 0.f};

    const s16x8* wfrag = (const s16x8*)WF;

    #pragma unroll
    for (int kk = 0; kk < 4; kk++) {
        #pragma unroll
        for (int nt = 0; nt < 8; nt++) {
            s16x8 bf = wfrag[(nt * 4 + kk) * 64 + lane];
            acc[0][nt] = __builtin_amdgcn_mfma_f32_16x16x32_bf16(bf, af[0][kk], acc[0][nt], 0, 0, 0);
            acc[1][nt] = __builtin_amdgcn_mfma_f32_16x16x32_bf16(bf, af[1][kk], acc[1][nt], 0, 0, 0);
        }
    }

    #pragma unroll
    for (int mt = 0; mt < 2; mt++) {
        int grow = rowBase + mt * 16 + ll;
        if (grow < NN) {
            float dn = dis[grow];
            unsigned* orow = (unsigned*)((char*)hs + ((unsigned)grow * 128u));
            #pragma unroll
            for (int nt = 0; nt < 8; nt++) {
                f32x4 v = acc[mt][nt];
                int u = 0;
                u = __builtin_amdgcn_cvt_pk_fp8_f32(v[0] * dn, v[1] * dn, u, false);
                u = __builtin_amdgcn_cvt_pk_fp8_f32(v[2] * dn, v[3] * dn, u, true);
                orow[nt * 4 + lg] = (unsigned)u;
            }
        }
    }
}

// ---------------- Fused agg1 + wsum: branch-free inner loop (round-16 form) ----------------

__global__ __launch_bounds__(256) void k_agg1(const unsigned* __restrict__ hs4, const float* __restrict__ dis,
                                              const int* __restrict__ offs, const int* __restrict__ oend,
                                              const int* __restrict__ csr, const float* __restrict__ bias,
                                              const float* __restrict__ coef, float* __restrict__ partials) {
    __shared__ float red[4][DD];
    int lane = threadIdx.x & 63;
    int half = lane >> 5;
    int li = lane & 31;
    int wv = threadIdx.x >> 6;
    int node0 = (blockIdx.x * 4 + wv) * 4;
    unsigned li4 = (unsigned)li << 2;
    const char* hb = (const char*)hs4;
    f32x2 v01 = {0.f, 0.f}, v23 = {0.f, 0.f};
    f32x4 bv = *(const f32x4*)&bias[li * 4];

    #pragma unroll 1
    for (int q = 0; q < 4; q++) {
        int node = node0 + q;
        int beg = offs[node], endp = oend[node];
        float dn = dis[node];
        f32x2 a01 = {0.f, 0.f}, a23 = {0.f, 0.f};

        #pragma unroll 1
        for (int i = beg; i < endp; i += 16) {
            const int* cp = csr + i + half * 8;
            int4 sa = *(const int4*)cp;
            int4 sb = *(const int4*)(cp + 4);
            unsigned r[8];
            r[0] = *(const unsigned*)(hb + (((unsigned)sa.x << 7) + li4));
            r[1] = *(const unsigned*)(hb + (((unsigned)sa.y << 7) + li4));
            r[2] = *(const unsigned*)(hb + (((unsigned)sa.z << 7) + li4));
            r[3] = *(const unsigned*)(hb + (((unsigned)sa.w << 7) + li4));
            r[4] = *(const unsigned*)(hb + (((unsigned)sb.x << 7) + li4));
            r[5] = *(const unsigned*)(hb + (((unsigned)sb.y << 7) + li4));
            r[6] = *(const unsigned*)(hb + (((unsigned)sb.z << 7) + li4));
            r[7] = *(const unsigned*)(hb + (((unsigned)sb.w << 7) + li4));
            #pragma unroll
            for (int j = 0; j < 8; j++) {
                a01 += __builtin_amdgcn_cvt_pk_f32_fp8(r[j], false);
                a23 += __builtin_amdgcn_cvt_pk_f32_fp8(r[j], true);
            }
        }

        a01[0] += __shfl_xor(a01[0], 32);
        a01[1] += __shfl_xor(a01[1], 32);
        a23[0] += __shfl_xor(a23[0], 32);
        a23[1] += __shfl_xor(a23[1], 32);

        if (half == 0) {
            unsigned su = *(const unsigned*)(hb + (((unsigned)node << 7) + li4));
            f32x2 sl = __builtin_amdgcn_cvt_pk_f32_fp8(su, false);
            f32x2 sh = __builtin_amdgcn_cvt_pk_f32_fp8(su, true);
            float o0 = fmaxf(dn * (a01[0] + sl[0]) + bv[0], 0.f);
            float o1 = fmaxf(dn * (a01[1] + sl[1]) + bv[1], 0.f);
            float o2 = fmaxf(dn * (a23[0] + sh[0]) + bv[2], 0.f);
            float o3 = fmaxf(dn * (a23[1] + sh[1]) + bv[3], 0.f);
            float wt = (coef[node] + dn) * dn;
            v01[0] += wt * o0; v01[1] += wt * o1;
            v23[0] += wt * o2; v23[1] += wt * o3;
        }
    }

    if (half == 0) {
        red[wv][li * 4 + 0] = v01[0];
        red[wv][li * 4 + 1] = v01[1];
        red[wv][li * 4 + 2] = v23[0];
        red[wv][li * 4 + 3] = v23[1];
    }
    __syncthreads();
    int t = threadIdx.x;
    if (t < DD)
        partials[(size_t)blockIdx.x * DD + t] = red[0][t] + red[1][t] + red[2][t] + red[3][t];
}

// ---------------- reductions + final matvec ----------------

__global__ __launch_bounds__(128) void k_red1(const float* __restrict__ partials, float* __restrict__ s1) {
    int t = threadIdx.x, b = blockIdx.x;
    float s = 0.f;
    for (int r = b * 50; r < b * 50 + 50; r++) s += partials[(size_t)r * DD + t];
    s1[b * DD + t] = s;
}

__global__ __launch_bounds__(128) void k_out(const float* __restrict__ s1, const float* __restrict__ W2,
                                             const float* __restrict__ b2, float* __restrict__ out) {
    __shared__ float v[DD];
    int t = threadIdx.x;
    float s = 0.f;
    for (int r = 0; r < NRB; r++) s += s1[r * DD + t];
    v[t] = s * (1.0f / NN);
    __syncthreads();
    float o = b2[t];
    for (int k = 0; k < DD; k++) o += v[k] * W2[k * DD + t];
    out[t] = o;
}

// ---------------- launch ----------------

extern "C" void kernel_launch(void* const* d_in, const int* in_sizes, int n_in,
                              void* d_out, int out_size, void* d_ws, size_t ws_size,
                              hipStream_t stream) {
    const float* x  = (const float*)d_in[0];
    const int*   ei = (const int*)d_in[1];
    const float* W1 = (const float*)d_in[2];
    const float* b1 = (const float*)d_in[3];
    const float* W2 = (const float*)d_in[4];
    const float* b2 = (const float*)d_in[5];
    float* out = (float*)d_out;
    const int* esrc = ei;
    const int* edst = ei + NE;

    char* p = (char*)d_ws;
    unsigned* part  = (unsigned*)p;      p += (size_t)NB * CAP * 4;
    unsigned* part2 = (unsigned*)p;      p += (size_t)NBS * CAP2 * 4;
    int* csr       = (int*)p;            p += (size_t)(NB * CAPP + 16) * 4;
    int* offs      = (int*)p;            p += (((size_t)NN * 4) + 255) & ~(size_t)255;
    int* oend      = (int*)p;            p += (((size_t)NN * 4) + 255) & ~(size_t)255;
    float* dis     = (float*)p;          p += (((size_t)NN * 4) + 255) & ~(size_t)255;
    float* coef    = (float*)p;          p += (((size_t)NN * 4) + 255) & ~(size_t)255;
    int* bcursor   = (int*)p;            p += (((size_t)(NB + NBS) * 4) + 255) & ~(size_t)255;
    unsigned* hs   = (unsigned*)p;       p += (size_t)(NN + 1) * DD;    // fp8 rows + zero dummy row
    float* partials = (float*)p;         p += (size_t)NAB * DD * 4;
    float* s1      = (float*)p;          p += (size_t)NRB * DD * 4;
    int* bcursor2  = bcursor + NB;

    hipMemsetAsync(bcursor, 0, (NB + NBS) * 4, stream);

    k_part<<<(NE + 4095) / 4096, 256, 0, stream>>>(esrc, edst, bcursor, bcursor2, part, part2);
    k_csr<<<NB, 256, 0, stream>>>(part, bcursor, offs, oend, dis, csr, hs);

    k_gemmcoef<<<NBS + NGB, 256, 0, stream>>>(x, W1, dis, hs, part2, bcursor2, coef);
    k_agg1<<<NAB, 256, 0, stream>>>(hs, dis, offs, oend, csr, b1, coef, partials);

    k_red1<<<NRB, 128, 0, stream>>>(partials, s1);
    k_out<<<1, 128, 0, stream>>>(s1, W2, b2, out);
}

// Round 20
// 141.401 us; speedup vs baseline: 1.1158x; 1.0790x over previous
//
#include <hip/hip_runtime.h>

#define NN 100000
#define NE 1600000
#define DD 128
#define BSH 8           // dst bucket = 256 nodes
#define NB 391          // ceil(NN/256)
#define CAP 4608        // per-dst-bucket partition capacity (mean 4092, +8 sigma)
#define CAPP 8704       // per-dst-bucket csr capacity incl. per-node pad-to-16 (mean ~6140)
#define SSH 9           // src bucket = 512 nodes
#define NBS 196         // ceil(NN/512)
#define CAP2 9472       // per-src-bucket capacity (mean 8163, +14 sigma)
#define NGB 782         // gemm blocks: ceil(NN/128)
#define NAB 6250        // agg1 blocks: 6250 * 4 waves * 4 nodes = 100000
#define NRB 125         // red1 blocks (each sums 50 partial rows)

typedef float f32x2 __attribute__((ext_vector_type(2)));
typedef float f32x4 __attribute__((ext_vector_type(4)));
typedef short s16x8 __attribute__((ext_vector_type(8)));

static __device__ __forceinline__ unsigned short f2bf(float f) {
    unsigned u = __float_as_uint(f);
    return (unsigned short)((u + 0x7fffu + ((u >> 16) & 1u)) >> 16);
}

// ---------------- dual partition: dst-stream (391 buckets) + src-stream (196 buckets) ----------------
// dst record = (local_dst 8b << 17) | src 17b ; src record = (local_src 9b << 17) | dst 17b

__global__ __launch_bounds__(256) void k_part(const int* __restrict__ src, const int* __restrict__ dst,
                                              int* __restrict__ bcursor, int* __restrict__ bcursor2,
                                              unsigned* __restrict__ part, unsigned* __restrict__ part2) {
    __shared__ int histD[NB], rankD[NB], bblD[NB];
    __shared__ int histS[NBS], rankS[NBS], bblS[NBS];
    int t = threadIdx.x;
    for (int j = t; j < NB; j += 256) histD[j] = 0;
    if (t < NBS) histS[t] = 0;
    __syncthreads();
    int base = blockIdx.x * 4096;
    int s[16], d[16];
    #pragma unroll
    for (int j = 0; j < 16; j++) {
        int i = base + j * 256 + t;
        if (i < NE) {
            s[j] = src[i]; d[j] = dst[i];
            atomicAdd(&histD[d[j] >> BSH], 1);
            atomicAdd(&histS[s[j] >> SSH], 1);
        } else d[j] = -1;
    }
    __syncthreads();
    for (int j = t; j < NB; j += 256) { bblD[j] = atomicAdd(&bcursor[j], histD[j]);  rankD[j] = 0; }
    if (t < NBS) { bblS[t] = atomicAdd(&bcursor2[t], histS[t]); rankS[t] = 0; }
    __syncthreads();
    #pragma unroll
    for (int j = 0; j < 16; j++) {
        if (d[j] >= 0) {
            int bD = d[j] >> BSH;
            int r = bblD[bD] + atomicAdd(&rankD[bD], 1);
            if (r < CAP)
                part[(size_t)bD * CAP + r] = (unsigned)s[j] | ((unsigned)(d[j] & 255) << 17);
            int bS = s[j] >> SSH;
            int r2 = bblS[bS] + atomicAdd(&rankS[bS], 1);
            if (r2 < CAP2)
                part2[(size_t)bS * CAP2 + r2] = (unsigned)d[j] | ((unsigned)(s[j] & 511) << 17);
        }
    }
}

// ---------------- per-bucket (256 nodes) CSR + scatter, per-node segments padded to 16 ----------------
// Pad entries hold NN (zero dummy hs row) so agg1's inner loop needs no bounds checks.

__global__ __launch_bounds__(256) void k_csr(const unsigned* __restrict__ part, const int* __restrict__ bcursor,
                                             int* __restrict__ offs, int* __restrict__ oend,
                                             float* __restrict__ dis, int* __restrict__ csr,
                                             unsigned* __restrict__ hs) {
    __shared__ int cnt[256], offl[256], s2[256];
    int t = threadIdx.x;
    int b = blockIdx.x;
    if (b == 0 && t < 32) hs[(unsigned)NN * 32u + t] = 0u;   // zero dummy row (before k_agg1)
    int dlo = b << BSH;
    int nn_b = NN - dlo; if (nn_b > 256) nn_b = 256;
    int c = bcursor[b]; if (c > CAP) c = CAP;
    size_t e0 = (size_t)b * CAP;
    int e0p = b * CAPP;
    cnt[t] = 0;
    __syncthreads();
    for (int i = t; i < c; i += 256)
        atomicAdd(&cnt[part[e0 + i] >> 17], 1);
    __syncthreads();
    int a = cnt[t];
    int ap = (a + 15) & ~15;
    s2[t] = ap;
    __syncthreads();
    for (int off = 1; off < 256; off <<= 1) {
        int add = (t >= off) ? s2[t - off] : 0;
        __syncthreads();
        s2[t] += add;
        __syncthreads();
    }
    int ex = s2[t] - ap;
    offl[t] = ex;
    if (t < nn_b) {
        offs[dlo + t] = e0p + ex;
        oend[dlo + t] = e0p + ex + ap;       // padded end = loop bound
        dis[dlo + t] = rsqrtf((float)a + 1.0f);
    }
    cnt[t] = 0;
    __syncthreads();
    for (int i = t; i < c; i += 256) {
        unsigned e = part[e0 + i];
        int li = (int)(e >> 17);
        int p = e0p + offl[li] + atomicAdd(&cnt[li], 1);
        csr[p] = (int)(e & 0x1FFFFu);
    }
    __syncthreads();
    if (t < nn_b) {
        int base2 = e0p + offl[t];
        for (int i = a; i < ap; i++) csr[base2 + i] = NN;   // pad with dummy index
    }
}

// ---------------- merged: blocks [0,NBS) = coef; [NBS,NBS+NGB) = MFMA GEMM ----------------

__global__ __launch_bounds__(256) void k_gemmcoef(const float* __restrict__ Ap, const float* __restrict__ W,
                                                  const float* __restrict__ dis, unsigned* __restrict__ hs,
                                                  const unsigned* __restrict__ part2, const int* __restrict__ bcursor2,
                                                  float* __restrict__ coef) {
    __shared__ unsigned WF[8192];   // gemm: 32KB bf16 W fragments; coef branch reuses as float accL
    int tid = threadIdx.x;
    if (blockIdx.x < NBS) {
        // ---- coef branch (src-buckets, LDS f32 accumulation) ----
        float* accL = (float*)WF;
        int b = blockIdx.x;
        int dlo = b << SSH;
        int nn_b = NN - dlo; if (nn_b > 512) nn_b = 512;
        int c = bcursor2[b]; if (c > CAP2) c = CAP2;
        size_t e0 = (size_t)b * CAP2;
        accL[tid] = 0.f; accL[tid + 256] = 0.f;
        __syncthreads();
        for (int i = tid; i < c; i += 256) {
            unsigned e = part2[e0 + i];
            atomicAdd(&accL[e >> 17], dis[e & 0x1FFFFu]);
        }
        __syncthreads();
        #pragma unroll
        for (int q = 0; q < 2; q++) {
            int i = tid + q * 256;
            if (i < nn_b) coef[dlo + i] = accL[i];
        }
        return;
    }

    // ---- gemm branch ----
    int gb = blockIdx.x - NBS;
    #pragma unroll
    for (int i = 0; i < 32; i++) {
        int e = i * 256 + tid;
        int jw = e & 3, lane = (e >> 2) & 63, kk = (e >> 8) & 3, nt = e >> 10;
        int r0 = kk * 32 + ((lane >> 4) << 3) + (jw << 1);
        int c = (nt << 4) + (lane & 15);
        unsigned lo = f2bf(W[r0 * DD + c]);
        unsigned hi = f2bf(W[(r0 + 1) * DD + c]);
        WF[e] = lo | (hi << 16);
    }

    int lane = tid & 63;
    int w = tid >> 6;
    int rowBase = gb * 128 + w * 32;
    int lg = lane >> 4;
    int ll = lane & 15;

    // load + convert x to bf16 fragments before the barrier (overlaps W staging wait)
    s16x8 af[2][4];
    #pragma unroll
    for (int mt = 0; mt < 2; mt++) {
        int r = rowBase + mt * 16 + ll;
        if (r >= NN) r = NN - 1;
        const char* xp = (const char*)Ap + ((unsigned)r * 512u + (unsigned)lg * 32u);
        #pragma unroll
        for (int kk = 0; kk < 4; kk++) {
            f32x4 a0 = *(const f32x4*)(xp + kk * 128);
            f32x4 a1 = *(const f32x4*)(xp + kk * 128 + 16);
            s16x8 tt;
            tt[0] = (short)f2bf(a0[0]); tt[1] = (short)f2bf(a0[1]);
            tt[2] = (short)f2bf(a0[2]); tt[3] = (short)f2bf(a0[3]);
            tt[4] = (short)f2bf(a1[0]); tt[5] = (short)f2bf(a1[1]);
            tt[6] = (short)f2bf(a1[2]); tt[7] = (short)f2bf(a1[3]);
            af[mt][kk] = tt;
        }
    }
    __syncthreads();

    f32x4 acc[2][8];
    #pragma unroll
    for (int m = 0; m < 2; m++)
        #pragma unroll
        for (int n = 0; n < 8; n++) acc[m][n] = (f32x4){0.f, 0.f, 0.f, 0.f};

    const s16x8* wfrag = (const s16x8*)WF;

    #pragma unroll
    for (int kk = 0; kk < 4; kk++) {
        #pragma unroll
        for (int nt = 0; nt < 8; nt++) {
            s16x8 bf = wfrag[(nt * 4 + kk) * 64 + lane];
            acc[0][nt] = __builtin_amdgcn_mfma_f32_16x16x32_bf16(bf, af[0][kk], acc[0][nt], 0, 0, 0);
            acc[1][nt] = __builtin_amdgcn_mfma_f32_16x16x32_bf16(bf, af[1][kk], acc[1][nt], 0, 0, 0);
        }
    }

    #pragma unroll
    for (int mt = 0; mt < 2; mt++) {
        int grow = rowBase + mt * 16 + ll;
        if (grow < NN) {
            float dn = dis[grow];
            unsigned* orow = (unsigned*)((char*)hs + ((unsigned)grow * 128u));
            #pragma unroll
            for (int nt = 0; nt < 8; nt++) {
                f32x4 v = acc[mt][nt];
                int u = 0;
                u = __builtin_amdgcn_cvt_pk_fp8_f32(v[0] * dn, v[1] * dn, u, false);
                u = __builtin_amdgcn_cvt_pk_fp8_f32(v[2] * dn, v[3] * dn, u, true);
                orow[nt * 4 + lg] = (unsigned)u;
            }
        }
    }
}

// ---------------- Fused agg1 + wsum: branch-free inner loop ----------------

__global__ __launch_bounds__(256) void k_agg1(const unsigned* __restrict__ hs4, const float* __restrict__ dis,
                                              const int* __restrict__ offs, const int* __restrict__ oend,
                                              const int* __restrict__ csr, const float* __restrict__ bias,
                                              const float* __restrict__ coef, float* __restrict__ partials) {
    __shared__ float red[4][DD];
    int lane = threadIdx.x & 63;
    int half = lane >> 5;
    int li = lane & 31;
    int wv = threadIdx.x >> 6;
    int node0 = (blockIdx.x * 4 + wv) * 4;
    unsigned li4 = (unsigned)li << 2;
    const char* hb = (const char*)hs4;
    f32x2 v01 = {0.f, 0.f}, v23 = {0.f, 0.f};
    f32x4 bv = *(const f32x4*)&bias[li * 4];

    #pragma unroll 1
    for (int q = 0; q < 4; q++) {
        int node = node0 + q;
        int beg = offs[node], endp = oend[node];
        float dn = dis[node];
        f32x2 a01 = {0.f, 0.f}, a23 = {0.f, 0.f};

        #pragma unroll 1
        for (int i = beg; i < endp; i += 16) {
            const int* cp = csr + i + half * 8;
            int4 sa = *(const int4*)cp;
            int4 sb = *(const int4*)(cp + 4);
            unsigned r[8];
            r[0] = *(const unsigned*)(hb + (((unsigned)sa.x << 7) + li4));
            r[1] = *(const unsigned*)(hb + (((unsigned)sa.y << 7) + li4));
            r[2] = *(const unsigned*)(hb + (((unsigned)sa.z << 7) + li4));
            r[3] = *(const unsigned*)(hb + (((unsigned)sa.w << 7) + li4));
            r[4] = *(const unsigned*)(hb + (((unsigned)sb.x << 7) + li4));
            r[5] = *(const unsigned*)(hb + (((unsigned)sb.y << 7) + li4));
            r[6] = *(const unsigned*)(hb + (((unsigned)sb.z << 7) + li4));
            r[7] = *(const unsigned*)(hb + (((unsigned)sb.w << 7) + li4));
            #pragma unroll
            for (int j = 0; j < 8; j++) {
                a01 += __builtin_amdgcn_cvt_pk_f32_fp8(r[j], false);
                a23 += __builtin_amdgcn_cvt_pk_f32_fp8(r[j], true);
            }
        }

        a01[0] += __shfl_xor(a01[0], 32);
        a01[1] += __shfl_xor(a01[1], 32);
        a23[0] += __shfl_xor(a23[0], 32);
        a23[1] += __shfl_xor(a23[1], 32);

        if (half == 0) {
            unsigned su = *(const unsigned*)(hb + (((unsigned)node << 7) + li4));
            f32x2 sl = __builtin_amdgcn_cvt_pk_f32_fp8(su, false);
            f32x2 sh = __builtin_amdgcn_cvt_pk_f32_fp8(su, true);
            float o0 = fmaxf(dn * (a01[0] + sl[0]) + bv[0], 0.f);
            float o1 = fmaxf(dn * (a01[1] + sl[1]) + bv[1], 0.f);
            float o2 = fmaxf(dn * (a23[0] + sh[0]) + bv[2], 0.f);
            float o3 = fmaxf(dn * (a23[1] + sh[1]) + bv[3], 0.f);
            float wt = (coef[node] + dn) * dn;
            v01[0] += wt * o0; v01[1] += wt * o1;
            v23[0] += wt * o2; v23[1] += wt * o3;
        }
    }

    if (half == 0) {
        red[wv][li * 4 + 0] = v01[0];
        red[wv][li * 4 + 1] = v01[1];
        red[wv][li * 4 + 2] = v23[0];
        red[wv][li * 4 + 3] = v23[1];
    }
    __syncthreads();
    int t = threadIdx.x;
    if (t < DD)
        partials[(size_t)blockIdx.x * DD + t] = red[0][t] + red[1][t] + red[2][t] + red[3][t];
}

// ---------------- reductions + final matvec ----------------

__global__ __launch_bounds__(128) void k_red1(const float* __restrict__ partials, float* __restrict__ s1) {
    int t = threadIdx.x, b = blockIdx.x;
    float s = 0.f;
    for (int r = b * 50; r < b * 50 + 50; r++) s += partials[(size_t)r * DD + t];
    s1[b * DD + t] = s;
}

__global__ __launch_bounds__(128) void k_out(const float* __restrict__ s1, const float* __restrict__ W2,
                                             const float* __restrict__ b2, float* __restrict__ out) {
    __shared__ float v[DD];
    int t = threadIdx.x;
    float s = 0.f;
    for (int r = 0; r < NRB; r++) s += s1[r * DD + t];
    v[t] = s * (1.0f / NN);
    __syncthreads();
    float o = b2[t];
    for (int k = 0; k < DD; k++) o += v[k] * W2[k * DD + t];
    out[t] = o;
}

// ---------------- launch ----------------

extern "C" void kernel_launch(void* const* d_in, const int* in_sizes, int n_in,
                              void* d_out, int out_size, void* d_ws, size_t ws_size,
                              hipStream_t stream) {
    const float* x  = (const float*)d_in[0];
    const int*   ei = (const int*)d_in[1];
    const float* W1 = (const float*)d_in[2];
    const float* b1 = (const float*)d_in[3];
    const float* W2 = (const float*)d_in[4];
    const float* b2 = (const float*)d_in[5];
    float* out = (float*)d_out;
    const int* esrc = ei;
    const int* edst = ei + NE;

    char* p = (char*)d_ws;
    unsigned* part  = (unsigned*)p;      p += (size_t)NB * CAP * 4;
    unsigned* part2 = (unsigned*)p;      p += (size_t)NBS * CAP2 * 4;
    int* csr       = (int*)p;            p += (((size_t)(NB * CAPP + 16) * 4) + 255) & ~(size_t)255;  // 256B-aligned: keeps hs row-aligned to L2 lines
    int* offs      = (int*)p;            p += (((size_t)NN * 4) + 255) & ~(size_t)255;
    int* oend      = (int*)p;            p += (((size_t)NN * 4) + 255) & ~(size_t)255;
    float* dis     = (float*)p;          p += (((size_t)NN * 4) + 255) & ~(size_t)255;
    float* coef    = (float*)p;          p += (((size_t)NN * 4) + 255) & ~(size_t)255;
    int* bcursor   = (int*)p;            p += (((size_t)(NB + NBS) * 4) + 255) & ~(size_t)255;
    unsigned* hs   = (unsigned*)p;       p += (size_t)(NN + 1) * DD;    // fp8 rows + zero dummy row
    float* partials = (float*)p;         p += (size_t)NAB * DD * 4;
    float* s1      = (float*)p;          p += (size_t)NRB * DD * 4;
    int* bcursor2  = bcursor + NB;

    hipMemsetAsync(bcursor, 0, (NB + NBS) * 4, stream);

    k_part<<<(NE + 4095) / 4096, 256, 0, stream>>>(esrc, edst, bcursor, bcursor2, part, part2);
    k_csr<<<NB, 256, 0, stream>>>(part, bcursor, offs, oend, dis, csr, hs);

    k_gemmcoef<<<NBS + NGB, 256, 0, stream>>>(x, W1, dis, hs, part2, bcursor2, coef);
    k_agg1<<<NAB, 256, 0, stream>>>(hs, dis, offs, oend, csr, b1, coef, partials);

    k_red1<<<NRB, 128, 0, stream>>>(partials, s1);
    k_out<<<1, 128, 0, stream>>>(s1, W2, b2, out);
}

// Round 21
// 140.979 us; speedup vs baseline: 1.1192x; 1.0030x over previous
//
#include <hip/hip_runtime.h>

#define NN 100000
#define NE 1600000
#define DD 128
#define BSH 8           // dst bucket = 256 nodes
#define NB 391          // ceil(NN/256)
#define CAP 4608        // per-dst-bucket partition capacity (mean 4092, +8 sigma)
#define CAPP 8704       // per-dst-bucket csr capacity incl. per-node pad-to-16 (mean ~6140)
#define SSH 9           // src bucket = 512 nodes
#define NBS 196         // ceil(NN/512)
#define CAP2 9472       // per-src-bucket capacity (mean 8163, +14 sigma)
#define NGB 1563        // gemm blocks: ceil(NN/64), 16 rows per wave
#define NAB 6250        // agg1 blocks: 6250 * 4 waves * 4 nodes = 100000
#define NRB 125         // red1 blocks (each sums 50 partial rows)

typedef float f32x2 __attribute__((ext_vector_type(2)));
typedef float f32x4 __attribute__((ext_vector_type(4)));
typedef short s16x8 __attribute__((ext_vector_type(8)));

static __device__ __forceinline__ unsigned short f2bf(float f) {
    unsigned u = __float_as_uint(f);
    return (unsigned short)((u + 0x7fffu + ((u >> 16) & 1u)) >> 16);
}

// ---------------- dual partition: 512 threads/block (8 waves) for latency hiding ----------------
// Same 4096 edges/block and 391 blocks as before -> identical append-run structure and
// write amplification; only the per-block wave count (occupancy) changes.

__global__ __launch_bounds__(512) void k_part(const int* __restrict__ src, const int* __restrict__ dst,
                                              int* __restrict__ bcursor, int* __restrict__ bcursor2,
                                              unsigned* __restrict__ part, unsigned* __restrict__ part2) {
    __shared__ int histD[NB], rankD[NB], bblD[NB];
    __shared__ int histS[NBS], rankS[NBS], bblS[NBS];
    int t = threadIdx.x;
    if (t < NB) histD[t] = 0;
    if (t < NBS) histS[t] = 0;
    __syncthreads();
    int base = blockIdx.x * 4096;
    int s[8], d[8];
    #pragma unroll
    for (int j = 0; j < 8; j++) {
        int i = base + j * 512 + t;
        if (i < NE) {
            s[j] = src[i]; d[j] = dst[i];
            atomicAdd(&histD[d[j] >> BSH], 1);
            atomicAdd(&histS[s[j] >> SSH], 1);
        } else d[j] = -1;
    }
    __syncthreads();
    if (t < NB) { bblD[t] = atomicAdd(&bcursor[t], histD[t]); rankD[t] = 0; }
    if (t < NBS) { bblS[t] = atomicAdd(&bcursor2[t], histS[t]); rankS[t] = 0; }
    __syncthreads();
    #pragma unroll
    for (int j = 0; j < 8; j++) {
        if (d[j] >= 0) {
            int bD = d[j] >> BSH;
            int r = bblD[bD] + atomicAdd(&rankD[bD], 1);
            if (r < CAP)
                part[(size_t)bD * CAP + r] = (unsigned)s[j] | ((unsigned)(d[j] & 255) << 17);
            int bS = s[j] >> SSH;
            int r2 = bblS[bS] + atomicAdd(&rankS[bS], 1);
            if (r2 < CAP2)
                part2[(size_t)bS * CAP2 + r2] = (unsigned)d[j] | ((unsigned)(s[j] & 511) << 17);
        }
    }
}

// ---------------- per-bucket (256 nodes) CSR + scatter, per-node segments padded to 16 ----------------

__global__ __launch_bounds__(256) void k_csr(const unsigned* __restrict__ part, const int* __restrict__ bcursor,
                                             int* __restrict__ offs, int* __restrict__ oend,
                                             float* __restrict__ dis, int* __restrict__ csr,
                                             unsigned* __restrict__ hs) {
    __shared__ int cnt[256], offl[256], s2[256];
    int t = threadIdx.x;
    int b = blockIdx.x;
    if (b == 0 && t < 32) hs[(unsigned)NN * 32u + t] = 0u;   // zero dummy row (before k_agg1)
    int dlo = b << BSH;
    int nn_b = NN - dlo; if (nn_b > 256) nn_b = 256;
    int c = bcursor[b]; if (c > CAP) c = CAP;
    size_t e0 = (size_t)b * CAP;
    int e0p = b * CAPP;
    cnt[t] = 0;
    __syncthreads();
    for (int i = t; i < c; i += 256)
        atomicAdd(&cnt[part[e0 + i] >> 17], 1);
    __syncthreads();
    int a = cnt[t];
    int ap = (a + 15) & ~15;
    s2[t] = ap;
    __syncthreads();
    for (int off = 1; off < 256; off <<= 1) {
        int add = (t >= off) ? s2[t - off] : 0;
        __syncthreads();
        s2[t] += add;
        __syncthreads();
    }
    int ex = s2[t] - ap;
    offl[t] = ex;
    if (t < nn_b) {
        offs[dlo + t] = e0p + ex;
        oend[dlo + t] = e0p + ex + ap;       // padded end = loop bound
        dis[dlo + t] = rsqrtf((float)a + 1.0f);
    }
    cnt[t] = 0;
    __syncthreads();
    for (int i = t; i < c; i += 256) {
        unsigned e = part[e0 + i];
        int li = (int)(e >> 17);
        int p = e0p + offl[li] + atomicAdd(&cnt[li], 1);
        csr[p] = (int)(e & 0x1FFFFu);
    }
    __syncthreads();
    if (t < nn_b) {
        int base2 = e0p + offl[t];
        for (int i = a; i < ap; i++) csr[base2 + i] = NN;   // pad with dummy index
    }
}

// ---------------- merged: blocks [0,NBS) = coef; [NBS,NBS+NGB) = MFMA GEMM (16 rows/wave) ----------------

__global__ __launch_bounds__(256) void k_gemmcoef(const float* __restrict__ Ap, const float* __restrict__ W,
                                                  const float* __restrict__ dis, unsigned* __restrict__ hs,
                                                  const unsigned* __restrict__ part2, const int* __restrict__ bcursor2,
                                                  float* __restrict__ coef) {
    __shared__ unsigned WF[8192];   // gemm: 32KB bf16 W fragments; coef branch reuses as float accL
    int tid = threadIdx.x;
    if (blockIdx.x < NBS) {
        // ---- coef branch (src-buckets, LDS f32 accumulation) ----
        float* accL = (float*)WF;
        int b = blockIdx.x;
        int dlo = b << SSH;
        int nn_b = NN - dlo; if (nn_b > 512) nn_b = 512;
        int c = bcursor2[b]; if (c > CAP2) c = CAP2;
        size_t e0 = (size_t)b * CAP2;
        accL[tid] = 0.f; accL[tid + 256] = 0.f;
        __syncthreads();
        for (int i = tid; i < c; i += 256) {
            unsigned e = part2[e0 + i];
            atomicAdd(&accL[e >> 17], dis[e & 0x1FFFFu]);
        }
        __syncthreads();
        #pragma unroll
        for (int q = 0; q < 2; q++) {
            int i = tid + q * 256;
            if (i < nn_b) coef[dlo + i] = accL[i];
        }
        return;
    }

    // ---- gemm branch: 4 waves x 16 rows = 64 rows per block ----
    int gb = blockIdx.x - NBS;
    #pragma unroll
    for (int i = 0; i < 32; i++) {
        int e = i * 256 + tid;
        int jw = e & 3, lane = (e >> 2) & 63, kk = (e >> 8) & 3, nt = e >> 10;
        int r0 = kk * 32 + ((lane >> 4) << 3) + (jw << 1);
        int c = (nt << 4) + (lane & 15);
        unsigned lo = f2bf(W[r0 * DD + c]);
        unsigned hi = f2bf(W[(r0 + 1) * DD + c]);
        WF[e] = lo | (hi << 16);
    }

    int lane = tid & 63;
    int w = tid >> 6;
    int rowBase = gb * 64 + w * 16;
    int lg = lane >> 4;
    int ll = lane & 15;

    // load + convert x to bf16 fragments before the barrier (overlaps W staging wait)
    s16x8 af[4];
    {
        int r = rowBase + ll;
        if (r >= NN) r = NN - 1;
        const char* xp = (const char*)Ap + ((unsigned)r * 512u + (unsigned)lg * 32u);
        #pragma unroll
        for (int kk = 0; kk < 4; kk++) {
            f32x4 a0 = *(const f32x4*)(xp + kk * 128);
            f32x4 a1 = *(const f32x4*)(xp + kk * 128 + 16);
            s16x8 tt;
            tt[0] = (short)f2bf(a0[0]); tt[1] = (short)f2bf(a0[1]);
            tt[2] = (short)f2bf(a0[2]); tt[3] = (short)f2bf(a0[3]);
            tt[4] = (short)f2bf(a1[0]); tt[5] = (short)f2bf(a1[1]);
            tt[6] = (short)f2bf(a1[2]); tt[7] = (short)f2bf(a1[3]);
            af[kk] = tt;
        }
    }
    __syncthreads();

    f32x4 acc[8];
    #pragma unroll
    for (int n = 0; n < 8; n++) acc[n] = (f32x4){0.f, 0.f, 0.f, 0.f};

    const s16x8* wfrag = (const s16x8*)WF;

    #pragma unroll
    for (int kk = 0; kk < 4; kk++) {
        #pragma unroll
        for (int nt = 0; nt < 8; nt++) {
            s16x8 bf = wfrag[(nt * 4 + kk) * 64 + lane];
            acc[nt] = __builtin_amdgcn_mfma_f32_16x16x32_bf16(bf, af[kk], acc[nt], 0, 0, 0);
        }
    }

    {
        int grow = rowBase + ll;
        if (grow < NN) {
            float dn = dis[grow];
            unsigned* orow = (unsigned*)((char*)hs + ((unsigned)grow * 128u));
            #pragma unroll
            for (int nt = 0; nt < 8; nt++) {
                f32x4 v = acc[nt];
                int u = 0;
                u = __builtin_amdgcn_cvt_pk_fp8_f32(v[0] * dn, v[1] * dn, u, false);
                u = __builtin_amdgcn_cvt_pk_fp8_f32(v[2] * dn, v[3] * dn, u, true);
                orow[nt * 4 + lg] = (unsigned)u;
            }
        }
    }
}

// ---------------- Fused agg1 + wsum: branch-free inner loop ----------------

__global__ __launch_bounds__(256) void k_agg1(const unsigned* __restrict__ hs4, const float* __restrict__ dis,
                                              const int* __restrict__ offs, const int* __restrict__ oend,
                                              const int* __restrict__ csr, const float* __restrict__ bias,
                                              const float* __restrict__ coef, float* __restrict__ partials) {
    __shared__ float red[4][DD];
    int lane = threadIdx.x & 63;
    int half = lane >> 5;
    int li = lane & 31;
    int wv = threadIdx.x >> 6;
    int node0 = (blockIdx.x * 4 + wv) * 4;
    unsigned li4 = (unsigned)li << 2;
    const char* hb = (const char*)hs4;
    f32x2 v01 = {0.f, 0.f}, v23 = {0.f, 0.f};
    f32x4 bv = *(const f32x4*)&bias[li * 4];

    #pragma unroll 1
    for (int q = 0; q < 4; q++) {
        int node = node0 + q;
        int beg = offs[node], endp = oend[node];
        float dn = dis[node];
        f32x2 a01 = {0.f, 0.f}, a23 = {0.f, 0.f};

        #pragma unroll 1
        for (int i = beg; i < endp; i += 16) {
            const int* cp = csr + i + half * 8;
            int4 sa = *(const int4*)cp;
            int4 sb = *(const int4*)(cp + 4);
            unsigned r[8];
            r[0] = *(const unsigned*)(hb + (((unsigned)sa.x << 7) + li4));
            r[1] = *(const unsigned*)(hb + (((unsigned)sa.y << 7) + li4));
            r[2] = *(const unsigned*)(hb + (((unsigned)sa.z << 7) + li4));
            r[3] = *(const unsigned*)(hb + (((unsigned)sa.w << 7) + li4));
            r[4] = *(const unsigned*)(hb + (((unsigned)sb.x << 7) + li4));
            r[5] = *(const unsigned*)(hb + (((unsigned)sb.y << 7) + li4));
            r[6] = *(const unsigned*)(hb + (((unsigned)sb.z << 7) + li4));
            r[7] = *(const unsigned*)(hb + (((unsigned)sb.w << 7) + li4));
            #pragma unroll
            for (int j = 0; j < 8; j++) {
                a01 += __builtin_amdgcn_cvt_pk_f32_fp8(r[j], false);
                a23 += __builtin_amdgcn_cvt_pk_f32_fp8(r[j], true);
            }
        }

        a01[0] += __shfl_xor(a01[0], 32);
        a01[1] += __shfl_xor(a01[1], 32);
        a23[0] += __shfl_xor(a23[0], 32);
        a23[1] += __shfl_xor(a23[1], 32);

        if (half == 0) {
            unsigned su = *(const unsigned*)(hb + (((unsigned)node << 7) + li4));
            f32x2 sl = __builtin_amdgcn_cvt_pk_f32_fp8(su, false);
            f32x2 sh = __builtin_amdgcn_cvt_pk_f32_fp8(su, true);
            float o0 = fmaxf(dn * (a01[0] + sl[0]) + bv[0], 0.f);
            float o1 = fmaxf(dn * (a01[1] + sl[1]) + bv[1], 0.f);
            float o2 = fmaxf(dn * (a23[0] + sh[0]) + bv[2], 0.f);
            float o3 = fmaxf(dn * (a23[1] + sh[1]) + bv[3], 0.f);
            float wt = (coef[node] + dn) * dn;
            v01[0] += wt * o0; v01[1] += wt * o1;
            v23[0] += wt * o2; v23[1] += wt * o3;
        }
    }

    if (half == 0) {
        red[wv][li * 4 + 0] = v01[0];
        red[wv][li * 4 + 1] = v01[1];
        red[wv][li * 4 + 2] = v23[0];
        red[wv][li * 4 + 3] = v23[1];
    }
    __syncthreads();
    int t = threadIdx.x;
    if (t < DD)
        partials[(size_t)blockIdx.x * DD + t] = red[0][t] + red[1][t] + red[2][t] + red[3][t];
}

// ---------------- reductions + final matvec ----------------

__global__ __launch_bounds__(128) void k_red1(const float* __restrict__ partials, float* __restrict__ s1) {
    int t = threadIdx.x, b = blockIdx.x;
    float s = 0.f;
    for (int r = b * 50; r < b * 50 + 50; r++) s += partials[(size_t)r * DD + t];
    s1[b * DD + t] = s;
}

__global__ __launch_bounds__(128) void k_out(const float* __restrict__ s1, const float* __restrict__ W2,
                                             const float* __restrict__ b2, float* __restrict__ out) {
    __shared__ float v[DD];
    int t = threadIdx.x;
    float s = 0.f;
    for (int r = 0; r < NRB; r++) s += s1[r * DD + t];
    v[t] = s * (1.0f / NN);
    __syncthreads();
    float o = b2[t];
    for (int k = 0; k < DD; k++) o += v[k] * W2[k * DD + t];
    out[t] = o;
}

// ---------------- launch ----------------

extern "C" void kernel_launch(void* const* d_in, const int* in_sizes, int n_in,
                              void* d_out, int out_size, void* d_ws, size_t ws_size,
                              hipStream_t stream) {
    const float* x  = (const float*)d_in[0];
    const int*   ei = (const int*)d_in[1];
    const float* W1 = (const float*)d_in[2];
    const float* b1 = (const float*)d_in[3];
    const float* W2 = (const float*)d_in[4];
    const float* b2 = (const float*)d_in[5];
    float* out = (float*)d_out;
    const int* esrc = ei;
    const int* edst = ei + NE;

    char* p = (char*)d_ws;
    unsigned* part  = (unsigned*)p;      p += (size_t)NB * CAP * 4;
    unsigned* part2 = (unsigned*)p;      p += (size_t)NBS * CAP2 * 4;
    int* csr       = (int*)p;            p += (((size_t)(NB * CAPP + 16) * 4) + 255) & ~(size_t)255;  // 256B-aligned: keeps hs row-aligned to L2 lines
    int* offs      = (int*)p;            p += (((size_t)NN * 4) + 255) & ~(size_t)255;
    int* oend      = (int*)p;            p += (((size_t)NN * 4) + 255) & ~(size_t)255;
    float* dis     = (float*)p;          p += (((size_t)NN * 4) + 255) & ~(size_t)255;
    float* coef    = (float*)p;          p += (((size_t)NN * 4) + 255) & ~(size_t)255;
    int* bcursor   = (int*)p;            p += (((size_t)(NB + NBS) * 4) + 255) & ~(size_t)255;
    unsigned* hs   = (unsigned*)p;       p += (size_t)(NN + 1) * DD;    // fp8 rows + zero dummy row
    float* partials = (float*)p;         p += (size_t)NAB * DD * 4;
    float* s1      = (float*)p;          p += (size_t)NRB * DD * 4;
    int* bcursor2  = bcursor + NB;

    hipMemsetAsync(bcursor, 0, (NB + NBS) * 4, stream);

    k_part<<<(NE + 4095) / 4096, 512, 0, stream>>>(esrc, edst, bcursor, bcursor2, part, part2);
    k_csr<<<NB, 256, 0, stream>>>(part, bcursor, offs, oend, dis, csr, hs);

    k_gemmcoef<<<NBS + NGB, 256, 0, stream>>>(x, W1, dis, hs, part2, bcursor2, coef);
    k_agg1<<<NAB, 256, 0, stream>>>(hs, dis, offs, oend, csr, b1, coef, partials);

    k_red1<<<NRB, 128, 0, stream>>>(partials, s1);
    k_out<<<1, 128, 0, stream>>>(s1, W2, b2, out);
}

// Round 22
// 137.526 us; speedup vs baseline: 1.1472x; 1.0251x over previous
//
#include <hip/hip_runtime.h>

#define NN 100000
#define NE 1600000
#define DD 128
#define BSH 8           // dst bucket = 256 nodes
#define NB 391          // ceil(NN/256)
#define CAP 4608        // per-dst-bucket partition capacity (mean 4092, +8 sigma)
#define CAPP 8704       // per-dst-bucket csr capacity incl. per-node pad-to-16 (mean ~6140)
#define SSH 9           // src bucket = 512 nodes
#define NBS 196         // ceil(NN/512)
#define CAP2 9472       // per-src-bucket capacity (mean 8163, +14 sigma)
#define NGB 782         // gemm blocks: ceil(NN/128), 32 rows per wave (r20 known-good)
#define NAB 6250        // agg1 blocks: 6250 * 4 waves * 4 nodes = 100000
#define NRB 125         // red1 blocks (each sums 50 partial rows)

typedef float f32x2 __attribute__((ext_vector_type(2)));
typedef float f32x4 __attribute__((ext_vector_type(4)));
typedef short s16x8 __attribute__((ext_vector_type(8)));

static __device__ __forceinline__ unsigned short f2bf(float f) {
    unsigned u = __float_as_uint(f);
    return (unsigned short)((u + 0x7fffu + ((u >> 16) & 1u)) >> 16);
}

// ---------------- dual partition: 512 threads/block (8 waves) for latency hiding ----------------

__global__ __launch_bounds__(512) void k_part(const int* __restrict__ src, const int* __restrict__ dst,
                                              int* __restrict__ bcursor, int* __restrict__ bcursor2,
                                              unsigned* __restrict__ part, unsigned* __restrict__ part2) {
    __shared__ int histD[NB], rankD[NB], bblD[NB];
    __shared__ int histS[NBS], rankS[NBS], bblS[NBS];
    int t = threadIdx.x;
    if (t < NB) histD[t] = 0;
    if (t < NBS) histS[t] = 0;
    __syncthreads();
    int base = blockIdx.x * 4096;
    int s[8], d[8];
    #pragma unroll
    for (int j = 0; j < 8; j++) {
        int i = base + j * 512 + t;
        if (i < NE) {
            s[j] = src[i]; d[j] = dst[i];
            atomicAdd(&histD[d[j] >> BSH], 1);
            atomicAdd(&histS[s[j] >> SSH], 1);
        } else d[j] = -1;
    }
    __syncthreads();
    if (t < NB) { bblD[t] = atomicAdd(&bcursor[t], histD[t]); rankD[t] = 0; }
    if (t < NBS) { bblS[t] = atomicAdd(&bcursor2[t], histS[t]); rankS[t] = 0; }
    __syncthreads();
    #pragma unroll
    for (int j = 0; j < 8; j++) {
        if (d[j] >= 0) {
            int bD = d[j] >> BSH;
            int r = bblD[bD] + atomicAdd(&rankD[bD], 1);
            if (r < CAP)
                part[(size_t)bD * CAP + r] = (unsigned)s[j] | ((unsigned)(d[j] & 255) << 17);
            int bS = s[j] >> SSH;
            int r2 = bblS[bS] + atomicAdd(&rankS[bS], 1);
            if (r2 < CAP2)
                part2[(size_t)bS * CAP2 + r2] = (unsigned)d[j] | ((unsigned)(s[j] & 511) << 17);
        }
    }
}

// ---------------- per-bucket (256 nodes) CSR + scatter, per-node segments padded to 16 ----------------

__global__ __launch_bounds__(256) void k_csr(const unsigned* __restrict__ part, const int* __restrict__ bcursor,
                                             int* __restrict__ offs, int* __restrict__ oend,
                                             float* __restrict__ dis, int* __restrict__ csr,
                                             unsigned* __restrict__ hs) {
    __shared__ int cnt[256], offl[256], s2[256];
    int t = threadIdx.x;
    int b = blockIdx.x;
    if (b == 0 && t < 32) hs[(unsigned)NN * 32u + t] = 0u;   // zero dummy row (before k_agg1)
    int dlo = b << BSH;
    int nn_b = NN - dlo; if (nn_b > 256) nn_b = 256;
    int c = bcursor[b]; if (c > CAP) c = CAP;
    size_t e0 = (size_t)b * CAP;
    int e0p = b * CAPP;
    cnt[t] = 0;
    __syncthreads();
    for (int i = t; i < c; i += 256)
        atomicAdd(&cnt[part[e0 + i] >> 17], 1);
    __syncthreads();
    int a = cnt[t];
    int ap = (a + 15) & ~15;
    s2[t] = ap;
    __syncthreads();
    for (int off = 1; off < 256; off <<= 1) {
        int add = (t >= off) ? s2[t - off] : 0;
        __syncthreads();
        s2[t] += add;
        __syncthreads();
    }
    int ex = s2[t] - ap;
    offl[t] = ex;
    if (t < nn_b) {
        offs[dlo + t] = e0p + ex;
        oend[dlo + t] = e0p + ex + ap;       // padded end = loop bound
        dis[dlo + t] = rsqrtf((float)a + 1.0f);
    }
    cnt[t] = 0;
    __syncthreads();
    for (int i = t; i < c; i += 256) {
        unsigned e = part[e0 + i];
        int li = (int)(e >> 17);
        int p = e0p + offl[li] + atomicAdd(&cnt[li], 1);
        csr[p] = (int)(e & 0x1FFFFu);
    }
    __syncthreads();
    if (t < nn_b) {
        int base2 = e0p + offl[t];
        for (int i = a; i < ap; i++) csr[base2 + i] = NN;   // pad with dummy index
    }
}

// ---------------- merged: blocks [0,NBS) = coef; [NBS,NBS+NGB) = MFMA GEMM (2x16 rows/wave) ----------------

__global__ __launch_bounds__(256) void k_gemmcoef(const float* __restrict__ Ap, const float* __restrict__ W,
                                                  const float* __restrict__ dis, unsigned* __restrict__ hs,
                                                  const unsigned* __restrict__ part2, const int* __restrict__ bcursor2,
                                                  float* __restrict__ coef) {
    __shared__ unsigned WF[8192];   // gemm: 32KB bf16 W fragments; coef branch reuses as float accL
    int tid = threadIdx.x;
    if (blockIdx.x < NBS) {
        // ---- coef branch (src-buckets, LDS f32 accumulation) ----
        float* accL = (float*)WF;
        int b = blockIdx.x;
        int dlo = b << SSH;
        int nn_b = NN - dlo; if (nn_b > 512) nn_b = 512;
        int c = bcursor2[b]; if (c > CAP2) c = CAP2;
        size_t e0 = (size_t)b * CAP2;
        accL[tid] = 0.f; accL[tid + 256] = 0.f;
        __syncthreads();
        for (int i = tid; i < c; i += 256) {
            unsigned e = part2[e0 + i];
            atomicAdd(&accL[e >> 17], dis[e & 0x1FFFFu]);
        }
        __syncthreads();
        #pragma unroll
        for (int q = 0; q < 2; q++) {
            int i = tid + q * 256;
            if (i < nn_b) coef[dlo + i] = accL[i];
        }
        return;
    }

    // ---- gemm branch: 4 waves x 32 rows = 128 rows per block ----
    int gb = blockIdx.x - NBS;
    #pragma unroll
    for (int i = 0; i < 32; i++) {
        int e = i * 256 + tid;
        int jw = e & 3, lane = (e >> 2) & 63, kk = (e >> 8) & 3, nt = e >> 10;
        int r0 = kk * 32 + ((lane >> 4) << 3) + (jw << 1);
        int c = (nt << 4) + (lane & 15);
        unsigned lo = f2bf(W[r0 * DD + c]);
        unsigned hi = f2bf(W[(r0 + 1) * DD + c]);
        WF[e] = lo | (hi << 16);
    }

    int lane = tid & 63;
    int w = tid >> 6;
    int rowBase = gb * 128 + w * 32;
    int lg = lane >> 4;
    int ll = lane & 15;

    // load + convert x to bf16 fragments before the barrier (overlaps W staging wait)
    s16x8 af[2][4];
    #pragma unroll
    for (int mt = 0; mt < 2; mt++) {
        int r = rowBase + mt * 16 + ll;
        if (r >= NN) r = NN - 1;
        const char* xp = (const char*)Ap + ((unsigned)r * 512u + (unsigned)lg * 32u);
        #pragma unroll
        for (int kk = 0; kk < 4; kk++) {
            f32x4 a0 = *(const f32x4*)(xp + kk * 128);
            f32x4 a1 = *(const f32x4*)(xp + kk * 128 + 16);
            s16x8 tt;
            tt[0] = (short)f2bf(a0[0]); tt[1] = (short)f2bf(a0[1]);
            tt[2] = (short)f2bf(a0[2]); tt[3] = (short)f2bf(a0[3]);
            tt[4] = (short)f2bf(a1[0]); tt[5] = (short)f2bf(a1[1]);
            tt[6] = (short)f2bf(a1[2]); tt[7] = (short)f2bf(a1[3]);
            af[mt][kk] = tt;
        }
    }
    __syncthreads();

    f32x4 acc[2][8];
    #pragma unroll
    for (int m = 0; m < 2; m++)
        #pragma unroll
        for (int n = 0; n < 8; n++) acc[m][n] = (f32x4){0.f, 0.f, 0.f, 0.f};

    const s16x8* wfrag = (const s16x8*)WF;

    #pragma unroll
    for (int kk = 0; kk < 4; kk++) {
        #pragma unroll
        for (int nt = 0; nt < 8; nt++) {
            s16x8 bf = wfrag[(nt * 4 + kk) * 64 + lane];
            acc[0][nt] = __builtin_amdgcn_mfma_f32_16x16x32_bf16(bf, af[0][kk], acc[0][nt], 0, 0, 0);
            acc[1][nt] = __builtin_amdgcn_mfma_f32_16x16x32_bf16(bf, af[1][kk], acc[1][nt], 0, 0, 0);
        }
    }

    #pragma unroll
    for (int mt = 0; mt < 2; mt++) {
        int grow = rowBase + mt * 16 + ll;
        if (grow < NN) {
            float dn = dis[grow];
            unsigned* orow = (unsigned*)((char*)hs + ((unsigned)grow * 128u));
            #pragma unroll
            for (int nt = 0; nt < 8; nt++) {
                f32x4 v = acc[mt][nt];
                int u = 0;
                u = __builtin_amdgcn_cvt_pk_fp8_f32(v[0] * dn, v[1] * dn, u, false);
                u = __builtin_amdgcn_cvt_pk_fp8_f32(v[2] * dn, v[3] * dn, u, true);
                orow[nt * 4 + lg] = (unsigned)u;
            }
        }
    }
}

// ---------------- Fused agg1 + wsum: branch-free inner loop ----------------

__global__ __launch_bounds__(256) void k_agg1(const unsigned* __restrict__ hs4, const float* __restrict__ dis,
                                              const int* __restrict__ offs, const int* __restrict__ oend,
                                              const int* __restrict__ csr, const float* __restrict__ bias,
                                              const float* __restrict__ coef, float* __restrict__ partials) {
    __shared__ float red[4][DD];
    int lane = threadIdx.x & 63;
    int half = lane >> 5;
    int li = lane & 31;
    int wv = threadIdx.x >> 6;
    int node0 = (blockIdx.x * 4 + wv) * 4;
    unsigned li4 = (unsigned)li << 2;
    const char* hb = (const char*)hs4;
    f32x2 v01 = {0.f, 0.f}, v23 = {0.f, 0.f};
    f32x4 bv = *(const f32x4*)&bias[li * 4];

    #pragma unroll 1
    for (int q = 0; q < 4; q++) {
        int node = node0 + q;
        int beg = offs[node], endp = oend[node];
        float dn = dis[node];
        f32x2 a01 = {0.f, 0.f}, a23 = {0.f, 0.f};

        #pragma unroll 1
        for (int i = beg; i < endp; i += 16) {
            const int* cp = csr + i + half * 8;
            int4 sa = *(const int4*)cp;
            int4 sb = *(const int4*)(cp + 4);
            unsigned r[8];
            r[0] = *(const unsigned*)(hb + (((unsigned)sa.x << 7) + li4));
            r[1] = *(const unsigned*)(hb + (((unsigned)sa.y << 7) + li4));
            r[2] = *(const unsigned*)(hb + (((unsigned)sa.z << 7) + li4));
            r[3] = *(const unsigned*)(hb + (((unsigned)sa.w << 7) + li4));
            r[4] = *(const unsigned*)(hb + (((unsigned)sb.x << 7) + li4));
            r[5] = *(const unsigned*)(hb + (((unsigned)sb.y << 7) + li4));
            r[6] = *(const unsigned*)(hb + (((unsigned)sb.z << 7) + li4));
            r[7] = *(const unsigned*)(hb + (((unsigned)sb.w << 7) + li4));
            #pragma unroll
            for (int j = 0; j < 8; j++) {
                a01 += __builtin_amdgcn_cvt_pk_f32_fp8(r[j], false);
                a23 += __builtin_amdgcn_cvt_pk_f32_fp8(r[j], true);
            }
        }

        a01[0] += __shfl_xor(a01[0], 32);
        a01[1] += __shfl_xor(a01[1], 32);
        a23[0] += __shfl_xor(a23[0], 32);
        a23[1] += __shfl_xor(a23[1], 32);

        if (half == 0) {
            unsigned su = *(const unsigned*)(hb + (((unsigned)node << 7) + li4));
            f32x2 sl = __builtin_amdgcn_cvt_pk_f32_fp8(su, false);
            f32x2 sh = __builtin_amdgcn_cvt_pk_f32_fp8(su, true);
            float o0 = fmaxf(dn * (a01[0] + sl[0]) + bv[0], 0.f);
            float o1 = fmaxf(dn * (a01[1] + sl[1]) + bv[1], 0.f);
            float o2 = fmaxf(dn * (a23[0] + sh[0]) + bv[2], 0.f);
            float o3 = fmaxf(dn * (a23[1] + sh[1]) + bv[3], 0.f);
            float wt = (coef[node] + dn) * dn;
            v01[0] += wt * o0; v01[1] += wt * o1;
            v23[0] += wt * o2; v23[1] += wt * o3;
        }
    }

    if (half == 0) {
        red[wv][li * 4 + 0] = v01[0];
        red[wv][li * 4 + 1] = v01[1];
        red[wv][li * 4 + 2] = v23[0];
        red[wv][li * 4 + 3] = v23[1];
    }
    __syncthreads();
    int t = threadIdx.x;
    if (t < DD)
        partials[(size_t)blockIdx.x * DD + t] = red[0][t] + red[1][t] + red[2][t] + red[3][t];
}

// ---------------- reductions + final matvec ----------------

__global__ __launch_bounds__(128) void k_red1(const float* __restrict__ partials, float* __restrict__ s1) {
    int t = threadIdx.x, b = blockIdx.x;
    float s = 0.f;
    for (int r = b * 50; r < b * 50 + 50; r++) s += partials[(size_t)r * DD + t];
    s1[b * DD + t] = s;
}

__global__ __launch_bounds__(128) void k_out(const float* __restrict__ s1, const float* __restrict__ W2,
                                             const float* __restrict__ b2, float* __restrict__ out) {
    __shared__ float v[DD];
    int t = threadIdx.x;
    float s = 0.f;
    for (int r = 0; r < NRB; r++) s += s1[r * DD + t];
    v[t] = s * (1.0f / NN);
    __syncthreads();
    float o = b2[t];
    for (int k = 0; k < DD; k++) o += v[k] * W2[k * DD + t];
    out[t] = o;
}

// ---------------- launch ----------------

extern "C" void kernel_launch(void* const* d_in, const int* in_sizes, int n_in,
                              void* d_out, int out_size, void* d_ws, size_t ws_size,
                              hipStream_t stream) {
    const float* x  = (const float*)d_in[0];
    const int*   ei = (const int*)d_in[1];
    const float* W1 = (const float*)d_in[2];
    const float* b1 = (const float*)d_in[3];
    const float* W2 = (const float*)d_in[4];
    const float* b2 = (const float*)d_in[5];
    float* out = (float*)d_out;
    const int* esrc = ei;
    const int* edst = ei + NE;

    char* p = (char*)d_ws;
    unsigned* part  = (unsigned*)p;      p += (size_t)NB * CAP * 4;
    unsigned* part2 = (unsigned*)p;      p += (size_t)NBS * CAP2 * 4;
    int* csr       = (int*)p;            p += (((size_t)(NB * CAPP + 16) * 4) + 255) & ~(size_t)255;  // 256B-aligned: keeps hs row-aligned to L2 lines
    int* offs      = (int*)p;            p += (((size_t)NN * 4) + 255) & ~(size_t)255;
    int* oend      = (int*)p;            p += (((size_t)NN * 4) + 255) & ~(size_t)255;
    float* dis     = (float*)p;          p += (((size_t)NN * 4) + 255) & ~(size_t)255;
    float* coef    = (float*)p;          p += (((size_t)NN * 4) + 255) & ~(size_t)255;
    int* bcursor   = (int*)p;            p += (((size_t)(NB + NBS) * 4) + 255) & ~(size_t)255;
    unsigned* hs   = (unsigned*)p;       p += (size_t)(NN + 1) * DD;    // fp8 rows + zero dummy row
    float* partials = (float*)p;         p += (size_t)NAB * DD * 4;
    float* s1      = (float*)p;          p += (size_t)NRB * DD * 4;
    int* bcursor2  = bcursor + NB;

    hipMemsetAsync(bcursor, 0, (NB + NBS) * 4, stream);

    k_part<<<(NE + 4095) / 4096, 512, 0, stream>>>(esrc, edst, bcursor, bcursor2, part, part2);
    k_csr<<<NB, 256, 0, stream>>>(part, bcursor, offs, oend, dis, csr, hs);

    k_gemmcoef<<<NBS + NGB, 256, 0, stream>>>(x, W1, dis, hs, part2, bcursor2, coef);
    k_agg1<<<NAB, 256, 0, stream>>>(hs, dis, offs, oend, csr, b1, coef, partials);

    k_red1<<<NRB, 128, 0, stream>>>(partials, s1);
    k_out<<<1, 128, 0, stream>>>(s1, W2, b2, out);
}

// Round 23
// 135.550 us; speedup vs baseline: 1.1640x; 1.0146x over previous
//
#include <hip/hip_runtime.h>

#define NN 100000
#define NE 1600000
#define DD 128
#define BSH 8           // dst bucket = 256 nodes
#define NB 391          // ceil(NN/256)
#define CAP 4608        // per-dst-bucket partition capacity (mean 4092, +8 sigma)
#define CAPP 8704       // per-dst-bucket csr capacity incl. per-node pad-to-16 (mean ~6140)
#define SSH 9           // src bucket = 512 nodes
#define NBS 196         // ceil(NN/512)
#define CAP2 9472       // per-src-bucket capacity (mean 8163, +14 sigma)
#define NEB 391         // k_part edge blocks: ceil(NE/4096)
#define NWPB 16         // k_part W-prep blocks: 8192 u32 / 512 threads
#define NGB 782         // gemm blocks: ceil(NN/128), 32 rows per wave
#define NAB 6250        // agg1 blocks: 6250 * 4 waves * 4 nodes = 100000
#define NRB 125         // red1 blocks (each sums 50 partial rows)

typedef float f32x2 __attribute__((ext_vector_type(2)));
typedef float f32x4 __attribute__((ext_vector_type(4)));
typedef short s16x8 __attribute__((ext_vector_type(8)));

static __device__ __forceinline__ unsigned short f2bf(float f) {
    unsigned u = __float_as_uint(f);
    return (unsigned short)((u + 0x7fffu + ((u >> 16) & 1u)) >> 16);
}

// ---------------- dual partition (8 waves/block) + W fragment pre-conversion ----------------
// blocks [0,NEB): partition edges; blocks [NEB,NEB+NWPB): convert W1 -> bf16 fragment layout.
// W-prep reads only input W1, writes only wbf (no cross-branch dependency).

__global__ __launch_bounds__(512) void k_part(const int* __restrict__ src, const int* __restrict__ dst,
                                              int* __restrict__ bcursor, int* __restrict__ bcursor2,
                                              unsigned* __restrict__ part, unsigned* __restrict__ part2,
                                              const float* __restrict__ W, unsigned* __restrict__ wbf) {
    __shared__ int histD[NB], rankD[NB], bblD[NB];
    __shared__ int histS[NBS], rankS[NBS], bblS[NBS];
    int t = threadIdx.x;
    if (blockIdx.x >= NEB) {
        int e = (blockIdx.x - NEB) * 512 + t;   // 0..8191
        int jw = e & 3, lane = (e >> 2) & 63, kk = (e >> 8) & 3, nt = e >> 10;
        int r0 = kk * 32 + ((lane >> 4) << 3) + (jw << 1);
        int c = (nt << 4) + (lane & 15);
        unsigned lo = f2bf(W[r0 * DD + c]);
        unsigned hi = f2bf(W[(r0 + 1) * DD + c]);
        wbf[e] = lo | (hi << 16);
        return;
    }
    if (t < NB) histD[t] = 0;
    if (t < NBS) histS[t] = 0;
    __syncthreads();
    int base = blockIdx.x * 4096;
    int s[8], d[8];
    #pragma unroll
    for (int j = 0; j < 8; j++) {
        int i = base + j * 512 + t;
        if (i < NE) {
            s[j] = src[i]; d[j] = dst[i];
            atomicAdd(&histD[d[j] >> BSH], 1);
            atomicAdd(&histS[s[j] >> SSH], 1);
        } else d[j] = -1;
    }
    __syncthreads();
    if (t < NB) { bblD[t] = atomicAdd(&bcursor[t], histD[t]); rankD[t] = 0; }
    if (t < NBS) { bblS[t] = atomicAdd(&bcursor2[t], histS[t]); rankS[t] = 0; }
    __syncthreads();
    #pragma unroll
    for (int j = 0; j < 8; j++) {
        if (d[j] >= 0) {
            int bD = d[j] >> BSH;
            int r = bblD[bD] + atomicAdd(&rankD[bD], 1);
            if (r < CAP)
                part[(size_t)bD * CAP + r] = (unsigned)s[j] | ((unsigned)(d[j] & 255) << 17);
            int bS = s[j] >> SSH;
            int r2 = bblS[bS] + atomicAdd(&rankS[bS], 1);
            if (r2 < CAP2)
                part2[(size_t)bS * CAP2 + r2] = (unsigned)d[j] | ((unsigned)(s[j] & 511) << 17);
        }
    }
}

// ---------------- per-bucket (256 nodes) CSR + scatter, per-node segments padded to 16 ----------------

__global__ __launch_bounds__(256) void k_csr(const unsigned* __restrict__ part, const int* __restrict__ bcursor,
                                             int* __restrict__ offs, int* __restrict__ oend,
                                             float* __restrict__ dis, int* __restrict__ csr,
                                             unsigned* __restrict__ hs) {
    __shared__ int cnt[256], offl[256], s2[256];
    int t = threadIdx.x;
    int b = blockIdx.x;
    if (b == 0 && t < 32) hs[(unsigned)NN * 32u + t] = 0u;   // zero dummy row (before k_agg1)
    int dlo = b << BSH;
    int nn_b = NN - dlo; if (nn_b > 256) nn_b = 256;
    int c = bcursor[b]; if (c > CAP) c = CAP;
    size_t e0 = (size_t)b * CAP;
    int e0p = b * CAPP;
    cnt[t] = 0;
    __syncthreads();
    for (int i = t; i < c; i += 256)
        atomicAdd(&cnt[part[e0 + i] >> 17], 1);
    __syncthreads();
    int a = cnt[t];
    int ap = (a + 15) & ~15;
    s2[t] = ap;
    __syncthreads();
    for (int off = 1; off < 256; off <<= 1) {
        int add = (t >= off) ? s2[t - off] : 0;
        __syncthreads();
        s2[t] += add;
        __syncthreads();
    }
    int ex = s2[t] - ap;
    offl[t] = ex;
    if (t < nn_b) {
        offs[dlo + t] = e0p + ex;
        oend[dlo + t] = e0p + ex + ap;       // padded end = loop bound
        dis[dlo + t] = rsqrtf((float)a + 1.0f);
    }
    cnt[t] = 0;
    __syncthreads();
    for (int i = t; i < c; i += 256) {
        unsigned e = part[e0 + i];
        int li = (int)(e >> 17);
        int p = e0p + offl[li] + atomicAdd(&cnt[li], 1);
        csr[p] = (int)(e & 0x1FFFFu);
    }
    __syncthreads();
    if (t < nn_b) {
        int base2 = e0p + offl[t];
        for (int i = a; i < ap; i++) csr[base2 + i] = NN;   // pad with dummy index
    }
}

// ---------------- merged: blocks [0,NBS) = coef; [NBS,NBS+NGB) = MFMA GEMM ----------------
// gemm stages pre-converted wbf via coalesced dwordx4 (no per-block f2bf prologue).

__global__ __launch_bounds__(256) void k_gemmcoef(const float* __restrict__ Ap, const unsigned* __restrict__ wbf,
                                                  const float* __restrict__ dis, unsigned* __restrict__ hs,
                                                  const unsigned* __restrict__ part2, const int* __restrict__ bcursor2,
                                                  float* __restrict__ coef) {
    __shared__ unsigned WF[8192];   // gemm: 32KB bf16 W fragments; coef branch reuses as float accL
    int tid = threadIdx.x;
    if (blockIdx.x < NBS) {
        // ---- coef branch (src-buckets, LDS f32 accumulation) ----
        float* accL = (float*)WF;
        int b = blockIdx.x;
        int dlo = b << SSH;
        int nn_b = NN - dlo; if (nn_b > 512) nn_b = 512;
        int c = bcursor2[b]; if (c > CAP2) c = CAP2;
        size_t e0 = (size_t)b * CAP2;
        accL[tid] = 0.f; accL[tid + 256] = 0.f;
        __syncthreads();
        for (int i = tid; i < c; i += 256) {
            unsigned e = part2[e0 + i];
            atomicAdd(&accL[e >> 17], dis[e & 0x1FFFFu]);
        }
        __syncthreads();
        #pragma unroll
        for (int q = 0; q < 2; q++) {
            int i = tid + q * 256;
            if (i < nn_b) coef[dlo + i] = accL[i];
        }
        return;
    }

    // ---- gemm branch: 4 waves x 32 rows = 128 rows per block ----
    int gb = blockIdx.x - NBS;
    {
        uint4* wf4 = (uint4*)WF;
        const uint4* wb4 = (const uint4*)wbf;
        #pragma unroll
        for (int i = 0; i < 8; i++) wf4[i * 256 + tid] = wb4[i * 256 + tid];
    }

    int lane = tid & 63;
    int w = tid >> 6;
    int rowBase = gb * 128 + w * 32;
    int lg = lane >> 4;
    int ll = lane & 15;

    // load + convert x to bf16 fragments before the barrier (overlaps W staging wait)
    s16x8 af[2][4];
    #pragma unroll
    for (int mt = 0; mt < 2; mt++) {
        int r = rowBase + mt * 16 + ll;
        if (r >= NN) r = NN - 1;
        const char* xp = (const char*)Ap + ((unsigned)r * 512u + (unsigned)lg * 32u);
        #pragma unroll
        for (int kk = 0; kk < 4; kk++) {
            f32x4 a0 = *(const f32x4*)(xp + kk * 128);
            f32x4 a1 = *(const f32x4*)(xp + kk * 128 + 16);
            s16x8 tt;
            tt[0] = (short)f2bf(a0[0]); tt[1] = (short)f2bf(a0[1]);
            tt[2] = (short)f2bf(a0[2]); tt[3] = (short)f2bf(a0[3]);
            tt[4] = (short)f2bf(a1[0]); tt[5] = (short)f2bf(a1[1]);
            tt[6] = (short)f2bf(a1[2]); tt[7] = (short)f2bf(a1[3]);
            af[mt][kk] = tt;
        }
    }
    __syncthreads();

    f32x4 acc[2][8];
    #pragma unroll
    for (int m = 0; m < 2; m++)
        #pragma unroll
        for (int n = 0; n < 8; n++) acc[m][n] = (f32x4){0.f, 0.f, 0.f, 0.f};

    const s16x8* wfrag = (const s16x8*)WF;

    #pragma unroll
    for (int kk = 0; kk < 4; kk++) {
        #pragma unroll
        for (int nt = 0; nt < 8; nt++) {
            s16x8 bf = wfrag[(nt * 4 + kk) * 64 + lane];
            acc[0][nt] = __builtin_amdgcn_mfma_f32_16x16x32_bf16(bf, af[0][kk], acc[0][nt], 0, 0, 0);
            acc[1][nt] = __builtin_amdgcn_mfma_f32_16x16x32_bf16(bf, af[1][kk], acc[1][nt], 0, 0, 0);
        }
    }

    #pragma unroll
    for (int mt = 0; mt < 2; mt++) {
        int grow = rowBase + mt * 16 + ll;
        if (grow < NN) {
            float dn = dis[grow];
            unsigned* orow = (unsigned*)((char*)hs + ((unsigned)grow * 128u));
            #pragma unroll
            for (int nt = 0; nt < 8; nt++) {
                f32x4 v = acc[mt][nt];
                int u = 0;
                u = __builtin_amdgcn_cvt_pk_fp8_f32(v[0] * dn, v[1] * dn, u, false);
                u = __builtin_amdgcn_cvt_pk_fp8_f32(v[2] * dn, v[3] * dn, u, true);
                orow[nt * 4 + lg] = (unsigned)u;
            }
        }
    }
}

// ---------------- Fused agg1 + wsum: branch-free inner loop ----------------

__global__ __launch_bounds__(256) void k_agg1(const unsigned* __restrict__ hs4, const float* __restrict__ dis,
                                              const int* __restrict__ offs, const int* __restrict__ oend,
                                              const int* __restrict__ csr, const float* __restrict__ bias,
                                              const float* __restrict__ coef, float* __restrict__ partials) {
    __shared__ float red[4][DD];
    int lane = threadIdx.x & 63;
    int half = lane >> 5;
    int li = lane & 31;
    int wv = threadIdx.x >> 6;
    int node0 = (blockIdx.x * 4 + wv) * 4;
    unsigned li4 = (unsigned)li << 2;
    const char* hb = (const char*)hs4;
    f32x2 v01 = {0.f, 0.f}, v23 = {0.f, 0.f};
    f32x4 bv = *(const f32x4*)&bias[li * 4];

    #pragma unroll 1
    for (int q = 0; q < 4; q++) {
        int node = node0 + q;
        int beg = offs[node], endp = oend[node];
        float dn = dis[node];
        f32x2 a01 = {0.f, 0.f}, a23 = {0.f, 0.f};

        #pragma unroll 1
        for (int i = beg; i < endp; i += 16) {
            const int* cp = csr + i + half * 8;
            int4 sa = *(const int4*)cp;
            int4 sb = *(const int4*)(cp + 4);
            unsigned r[8];
            r[0] = *(const unsigned*)(hb + (((unsigned)sa.x << 7) + li4));
            r[1] = *(const unsigned*)(hb + (((unsigned)sa.y << 7) + li4));
            r[2] = *(const unsigned*)(hb + (((unsigned)sa.z << 7) + li4));
            r[3] = *(const unsigned*)(hb + (((unsigned)sa.w << 7) + li4));
            r[4] = *(const unsigned*)(hb + (((unsigned)sb.x << 7) + li4));
            r[5] = *(const unsigned*)(hb + (((unsigned)sb.y << 7) + li4));
            r[6] = *(const unsigned*)(hb + (((unsigned)sb.z << 7) + li4));
            r[7] = *(const unsigned*)(hb + (((unsigned)sb.w << 7) + li4));
            #pragma unroll
            for (int j = 0; j < 8; j++) {
                a01 += __builtin_amdgcn_cvt_pk_f32_fp8(r[j], false);
                a23 += __builtin_amdgcn_cvt_pk_f32_fp8(r[j], true);
            }
        }

        a01[0] += __shfl_xor(a01[0], 32);
        a01[1] += __shfl_xor(a01[1], 32);
        a23[0] += __shfl_xor(a23[0], 32);
        a23[1] += __shfl_xor(a23[1], 32);

        if (half == 0) {
            unsigned su = *(const unsigned*)(hb + (((unsigned)node << 7) + li4));
            f32x2 sl = __builtin_amdgcn_cvt_pk_f32_fp8(su, false);
            f32x2 sh = __builtin_amdgcn_cvt_pk_f32_fp8(su, true);
            float o0 = fmaxf(dn * (a01[0] + sl[0]) + bv[0], 0.f);
            float o1 = fmaxf(dn * (a01[1] + sl[1]) + bv[1], 0.f);
            float o2 = fmaxf(dn * (a23[0] + sh[0]) + bv[2], 0.f);
            float o3 = fmaxf(dn * (a23[1] + sh[1]) + bv[3], 0.f);
            float wt = (coef[node] + dn) * dn;
            v01[0] += wt * o0; v01[1] += wt * o1;
            v23[0] += wt * o2; v23[1] += wt * o3;
        }
    }

    if (half == 0) {
        red[wv][li * 4 + 0] = v01[0];
        red[wv][li * 4 + 1] = v01[1];
        red[wv][li * 4 + 2] = v23[0];
        red[wv][li * 4 + 3] = v23[1];
    }
    __syncthreads();
    int t = threadIdx.x;
    if (t < DD)
        partials[(size_t)blockIdx.x * DD + t] = red[0][t] + red[1][t] + red[2][t] + red[3][t];
}

// ---------------- reductions + final matvec ----------------

__global__ __launch_bounds__(128) void k_red1(const float* __restrict__ partials, float* __restrict__ s1) {
    int t = threadIdx.x, b = blockIdx.x;
    float s = 0.f;
    for (int r = b * 50; r < b * 50 + 50; r++) s += partials[(size_t)r * DD + t];
    s1[b * DD + t] = s;
}

__global__ __launch_bounds__(128) void k_out(const float* __restrict__ s1, const float* __restrict__ W2,
                                             const float* __restrict__ b2, float* __restrict__ out) {
    __shared__ float v[DD];
    int t = threadIdx.x;
    float s = 0.f;
    for (int r = 0; r < NRB; r++) s += s1[r * DD + t];
    v[t] = s * (1.0f / NN);
    __syncthreads();
    float o = b2[t];
    for (int k = 0; k < DD; k++) o += v[k] * W2[k * DD + t];
    out[t] = o;
}

// ---------------- launch ----------------

extern "C" void kernel_launch(void* const* d_in, const int* in_sizes, int n_in,
                              void* d_out, int out_size, void* d_ws, size_t ws_size,
                              hipStream_t stream) {
    const float* x  = (const float*)d_in[0];
    const int*   ei = (const int*)d_in[1];
    const float* W1 = (const float*)d_in[2];
    const float* b1 = (const float*)d_in[3];
    const float* W2 = (const float*)d_in[4];
    const float* b2 = (const float*)d_in[5];
    float* out = (float*)d_out;
    const int* esrc = ei;
    const int* edst = ei + NE;

    char* p = (char*)d_ws;
    unsigned* part  = (unsigned*)p;      p += (size_t)NB * CAP * 4;
    unsigned* part2 = (unsigned*)p;      p += (size_t)NBS * CAP2 * 4;
    int* csr       = (int*)p;            p += (((size_t)(NB * CAPP + 16) * 4) + 255) & ~(size_t)255;  // 256B-aligned
    int* offs      = (int*)p;            p += (((size_t)NN * 4) + 255) & ~(size_t)255;
    int* oend      = (int*)p;            p += (((size_t)NN * 4) + 255) & ~(size_t)255;
    float* dis     = (float*)p;          p += (((size_t)NN * 4) + 255) & ~(size_t)255;
    float* coef    = (float*)p;          p += (((size_t)NN * 4) + 255) & ~(size_t)255;
    int* bcursor   = (int*)p;            p += (((size_t)(NB + NBS) * 4) + 255) & ~(size_t)255;
    unsigned* wbf  = (unsigned*)p;       p += (size_t)8192 * 4;          // pre-converted W fragments
    unsigned* hs   = (unsigned*)p;       p += (size_t)(NN + 1) * DD;     // fp8 rows + zero dummy row
    float* partials = (float*)p;         p += (size_t)NAB * DD * 4;
    float* s1      = (float*)p;          p += (size_t)NRB * DD * 4;
    int* bcursor2  = bcursor + NB;

    hipMemsetAsync(bcursor, 0, (NB + NBS) * 4, stream);

    k_part<<<NEB + NWPB, 512, 0, stream>>>(esrc, edst, bcursor, bcursor2, part, part2, W1, wbf);
    k_csr<<<NB, 256, 0, stream>>>(part, bcursor, offs, oend, dis, csr, hs);

    k_gemmcoef<<<NBS + NGB, 256, 0, stream>>>(x, wbf, dis, hs, part2, bcursor2, coef);
    k_agg1<<<NAB, 256, 0, stream>>>(hs, dis, offs, oend, csr, b1, coef, partials);

    k_red1<<<NRB, 128, 0, stream>>>(partials, s1);
    k_out<<<1, 128, 0, stream>>>(s1, W2, b2, out);
}